// Round 2
// baseline (392.480 us; speedup 1.0000x reference)
//
#include <hip/hip_runtime.h>

#define T_ 1024
#define B_ 4
#define E_ 512
#define H_ 8
#define D_ 64
#define P_ 64
#define K2 128            // 2P
#define N_ (T_*B_)        // 4096 rows (t*B + b)
#define CHK 64            // scan chunk length
#define NC (T_/CHK)       // 16 chunks
#define BH (B_*H_)        // 32
#define EPSV 1e-6f

typedef unsigned int uint;
typedef unsigned short ushort;

__device__ __forceinline__ float b2f(ushort u){ return __uint_as_float(((uint)u) << 16); }
__device__ __forceinline__ ushort f2b(float f){
  uint x = __float_as_uint(f);
  return (ushort)((x + 0x7fffu + ((x >> 16) & 1u)) >> 16);   // RNE
}
__device__ __forceinline__ float lo16(uint u){ return __uint_as_float(u << 16); }
__device__ __forceinline__ float hi16(uint u){ return __uint_as_float(u & 0xffff0000u); }

__device__ __forceinline__ float4 ld4(const float* p){ return *(const float4*)p; }
__device__ __forceinline__ float4 ld4(const ushort* p){
  const ushort4 u = *(const ushort4*)p;
  return make_float4(b2f(u.x), b2f(u.y), b2f(u.z), b2f(u.w));
}
__device__ __forceinline__ void st(float* p, float v){ *p = v; }
__device__ __forceinline__ void st(ushort* p, float v){ *p = f2b(v); }

// out[n,m] = sum_e A[n,e]*W[m,e] + bias[m]. A: f32 or bf16; W,bias f32; out f32 or bf16.
template<typename AT, typename OutT>
__global__ __launch_bounds__(256) void gemm_bias_kernel(
    const AT* __restrict__ A, const float* __restrict__ W,
    const float* __restrict__ bias, OutT* __restrict__ out,
    const int Mcols, const int Ed)
{
  __shared__ float As[16][68];
  __shared__ float Bs[16][68];
  const int tid = threadIdx.x;
  const int row0 = blockIdx.x * 64, col0 = blockIdx.y * 64;
  const int lr = tid >> 2, lk = (tid & 3) * 4;
  const int tr = tid >> 4, tc = tid & 15;
  float acc[4][4] = {};
  for (int k0 = 0; k0 < Ed; k0 += 16) {
    const float4 av = ld4(A + (size_t)(row0 + lr) * Ed + k0 + lk);
    const float4 wv = ld4(W + (size_t)(col0 + lr) * Ed + k0 + lk);
    As[lk + 0][lr] = av.x; As[lk + 1][lr] = av.y;
    As[lk + 2][lr] = av.z; As[lk + 3][lr] = av.w;
    Bs[lk + 0][lr] = wv.x; Bs[lk + 1][lr] = wv.y;
    Bs[lk + 2][lr] = wv.z; Bs[lk + 3][lr] = wv.w;
    __syncthreads();
    #pragma unroll
    for (int kk = 0; kk < 16; ++kk) {
      const float4 a4 = *(const float4*)(&As[kk][tr * 4]);
      const float4 b4 = *(const float4*)(&Bs[kk][tc * 4]);
      acc[0][0] += a4.x*b4.x; acc[0][1] += a4.x*b4.y; acc[0][2] += a4.x*b4.z; acc[0][3] += a4.x*b4.w;
      acc[1][0] += a4.y*b4.x; acc[1][1] += a4.y*b4.y; acc[1][2] += a4.y*b4.z; acc[1][3] += a4.y*b4.w;
      acc[2][0] += a4.z*b4.x; acc[2][1] += a4.z*b4.y; acc[2][2] += a4.z*b4.z; acc[2][3] += a4.z*b4.w;
      acc[3][0] += a4.w*b4.x; acc[3][1] += a4.w*b4.y; acc[3][2] += a4.w*b4.z; acc[3][3] += a4.w*b4.w;
    }
    __syncthreads();
  }
  #pragma unroll
  for (int j = 0; j < 4; ++j) {
    const float bj = bias[col0 + tc * 4 + j];
    #pragma unroll
    for (int i = 0; i < 4; ++i) {
      st(out + (size_t)(row0 + tr * 4 + i) * Mcols + col0 + tc * 4 + j, acc[i][j] + bj);
    }
  }
}

// One wave per (n,h): l2-normalize q/k head vector, project with rm[h], sin/cos -> bf16.
__global__ __launch_bounds__(256) void phi_kernel(
    const float* __restrict__ qf, const float* __restrict__ kf,
    const float* __restrict__ rm, ushort* __restrict__ pq, ushort* __restrict__ pk)
{
  const float* src = blockIdx.y ? kf : qf;
  ushort* dst = blockIdx.y ? pk : pq;
  __shared__ float xs[4][64];
  const int w = threadIdx.x >> 6, lane = threadIdx.x & 63;
  const int gid = blockIdx.x * 4 + w;   // n*H + h
  const int n = gid >> 3, h = gid & 7;
  const float val = src[(size_t)n * E_ + h * D_ + lane];
  float s2 = val * val;
  #pragma unroll
  for (int off = 32; off; off >>= 1) s2 += __shfl_xor(s2, off, 64);
  const float scale = 1.0f / fmaxf(sqrtf(s2), EPSV);
  xs[w][lane] = val * scale;
  __syncthreads();
  const float* rrow = rm + ((size_t)h * P_ + lane) * D_;  // lane = p
  float acc = 0.f;
  #pragma unroll
  for (int d0 = 0; d0 < D_; d0 += 8) {
    const float4 r0 = *(const float4*)(rrow + d0);
    const float4 r1 = *(const float4*)(rrow + d0 + 4);
    const float4 x0 = *(const float4*)(&xs[w][d0]);
    const float4 x1 = *(const float4*)(&xs[w][d0 + 4]);
    acc += x0.x*r0.x + x0.y*r0.y + x0.z*r0.z + x0.w*r0.w;
    acc += x1.x*r1.x + x1.y*r1.y + x1.z*r1.z + x1.w*r1.w;
  }
  const float sv = sinf(acc) * 0.125f;   // P^-0.5
  const float cv = cosf(acc) * 0.125f;
  const size_t base = ((size_t)n * H_ + h) * K2;
  dst[base + lane] = f2b(sv);
  dst[base + 64 + lane] = f2b(cv);
}

// Per-chunk sums: cS[c,bh,k,d] = sum_{t in chunk} pk[t,k]*v[t,d]; cz likewise.
__global__ __launch_bounds__(256) void chunk_sum_kernel(
    const ushort* __restrict__ pk, const ushort* __restrict__ v,
    float* __restrict__ cS, float* __restrict__ cz)
{
  const int c = blockIdx.x, bh = blockIdx.y, b = bh >> 3, h = bh & 7;
  __shared__ float pks[CHK][K2];
  __shared__ float vsh[CHK][D_];
  const int tid = threadIdx.x;
  for (int i = tid; i < CHK * K2; i += 256) {
    const int tt = i >> 7, k = i & 127;
    const int n = (c * CHK + tt) * B_ + b;
    pks[tt][k] = b2f(pk[((size_t)n * H_ + h) * K2 + k]);
  }
  for (int i = tid; i < CHK * D_; i += 256) {
    const int tt = i >> 6, d = i & 63;
    const int n = (c * CHK + tt) * B_ + b;
    vsh[tt][d] = b2f(v[(size_t)n * E_ + h * D_ + d]);
  }
  __syncthreads();
  const int d = tid & 63, kg = tid >> 6;   // kg: 0..3 (32 k's each)
  float acc[32] = {};
  for (int tt = 0; tt < CHK; ++tt) {
    const float vv = vsh[tt][d];
    const float4* pk4 = (const float4*)(&pks[tt][kg * 32]);
    #pragma unroll
    for (int i4 = 0; i4 < 8; ++i4) {
      const float4 p = pk4[i4];
      acc[i4*4+0] += p.x * vv; acc[i4*4+1] += p.y * vv;
      acc[i4*4+2] += p.z * vv; acc[i4*4+3] += p.w * vv;
    }
  }
  float* So = cS + (size_t)(c * BH + bh) * (K2 * D_);
  #pragma unroll
  for (int i = 0; i < 32; ++i) So[(kg * 32 + i) * D_ + d] = acc[i];
  if (tid < K2) {
    float zacc = 0.f;
    for (int tt = 0; tt < CHK; ++tt) zacc += pks[tt][tid];
    cz[(size_t)(c * BH + bh) * K2 + tid] = zacc;
  }
}

// In-place exclusive prefix over chunks (sequential over NC=16; parallel over bh, k*d).
__global__ __launch_bounds__(256) void prefix_kernel(
    float* __restrict__ cS, float* __restrict__ cz)
{
  const int bh = blockIdx.x, tid = threadIdx.x;
  float run[32];
  #pragma unroll
  for (int i = 0; i < 32; ++i) run[i] = 0.f;
  for (int c = 0; c < NC; ++c) {
    float* p = cS + (size_t)(c * BH + bh) * (K2 * D_);
    #pragma unroll
    for (int i = 0; i < 32; ++i) {
      const int e = i * 256 + tid;
      const float t = p[e];
      p[e] = run[i];
      run[i] += t;
    }
  }
  if (tid < K2) {
    float rz = 0.f;
    for (int c = 0; c < NC; ++c) {
      float* pz = cz + (size_t)(c * BH + bh) * K2 + tid;
      const float t = *pz;
      *pz = rz;
      rz += t;
    }
  }
}

// Per-chunk outputs: A = causal(pq@pk^T); attn = (A@v + pq@Sp) / max(rowsum(A)+pq@zp, eps)
__global__ __launch_bounds__(256) void chunk_out_kernel(
    const ushort* __restrict__ pq, const ushort* __restrict__ pkg,
    const ushort* __restrict__ v, const float* __restrict__ Sp,
    const float* __restrict__ zp, ushort* __restrict__ attn)
{
  const int c = blockIdx.x, bh = blockIdx.y, b = bh >> 3, h = bh & 7;
  __shared__ ushort pqs[CHK][K2];
  __shared__ ushort pks[CHK][K2];
  __shared__ ushort vs[CHK][D_];
  __shared__ float Am[CHK][CHK + 2];
  __shared__ float zps[K2];
  __shared__ float dens[CHK];
  const int tid = threadIdx.x;
  for (int i = tid; i < CHK * K2 / 8; i += 256) {
    const int tt = i >> 4, k8 = (i & 15) * 8;
    const int n = (c * CHK + tt) * B_ + b;
    const size_t off = ((size_t)n * H_ + h) * K2 + k8;
    *(uint4*)(&pqs[tt][k8]) = *(const uint4*)(pq + off);
    *(uint4*)(&pks[tt][k8]) = *(const uint4*)(pkg + off);
  }
  for (int i = tid; i < CHK * D_ / 8; i += 256) {
    const int tt = i >> 3, d8 = (i & 7) * 8;
    const int n = (c * CHK + tt) * B_ + b;
    *(uint4*)(&vs[tt][d8]) = *(const uint4*)(v + (size_t)n * E_ + h * D_ + d8);
  }
  if (tid < K2) zps[tid] = zp[(size_t)(c * BH + bh) * K2 + tid];
  __syncthreads();
  const int t = tid >> 2;
  {
    const int tg = tid & 3;
    float accA[16] = {};
    for (int k0 = 0; k0 < K2; k0 += 8) {
      const uint4 uq = *(const uint4*)(&pqs[t][k0]);
      const float p0 = lo16(uq.x), p1 = hi16(uq.x), p2 = lo16(uq.y), p3 = hi16(uq.y);
      const float p4 = lo16(uq.z), p5 = hi16(uq.z), p6 = lo16(uq.w), p7 = hi16(uq.w);
      #pragma unroll
      for (int j = 0; j < 16; ++j) {
        const uint4 uk = *(const uint4*)(&pks[tg * 16 + j][k0]);
        accA[j] += p0*lo16(uk.x) + p1*hi16(uk.x) + p2*lo16(uk.y) + p3*hi16(uk.y)
                 + p4*lo16(uk.z) + p5*hi16(uk.z) + p6*lo16(uk.w) + p7*hi16(uk.w);
      }
    }
    #pragma unroll
    for (int j = 0; j < 16; ++j) {
      const int tau = tg * 16 + j;
      Am[t][tau] = (tau <= t) ? accA[j] : 0.f;
    }
  }
  __syncthreads();
  const int dg = tid & 3, d0 = dg * 16;
  float num[16] = {};
  float dn = 0.f;
  for (int tau = 0; tau < CHK; ++tau) {
    const float a = Am[t][tau];
    dn += a;
    const uint4 u0 = *(const uint4*)(&vs[tau][d0]);
    const uint4 u1 = *(const uint4*)(&vs[tau][d0 + 8]);
    num[0]  += a*lo16(u0.x); num[1]  += a*hi16(u0.x);
    num[2]  += a*lo16(u0.y); num[3]  += a*hi16(u0.y);
    num[4]  += a*lo16(u0.z); num[5]  += a*hi16(u0.z);
    num[6]  += a*lo16(u0.w); num[7]  += a*hi16(u0.w);
    num[8]  += a*lo16(u1.x); num[9]  += a*hi16(u1.x);
    num[10] += a*lo16(u1.y); num[11] += a*hi16(u1.y);
    num[12] += a*lo16(u1.z); num[13] += a*hi16(u1.z);
    num[14] += a*lo16(u1.w); num[15] += a*hi16(u1.w);
  }
  const float* Srow = Sp + (size_t)(c * BH + bh) * (K2 * D_) + d0;
  for (int k = 0; k < K2; ++k) {
    const float pqv = b2f(pqs[t][k]);
    dn += pqv * zps[k];
    const float4 s0 = *(const float4*)(Srow + k * D_ + 0);
    const float4 s1 = *(const float4*)(Srow + k * D_ + 4);
    const float4 s2 = *(const float4*)(Srow + k * D_ + 8);
    const float4 s3 = *(const float4*)(Srow + k * D_ + 12);
    num[0]  += pqv*s0.x; num[1]  += pqv*s0.y; num[2]  += pqv*s0.z; num[3]  += pqv*s0.w;
    num[4]  += pqv*s1.x; num[5]  += pqv*s1.y; num[6]  += pqv*s1.z; num[7]  += pqv*s1.w;
    num[8]  += pqv*s2.x; num[9]  += pqv*s2.y; num[10] += pqv*s2.z; num[11] += pqv*s2.w;
    num[12] += pqv*s3.x; num[13] += pqv*s3.y; num[14] += pqv*s3.z; num[15] += pqv*s3.w;
  }
  if (dg == 0) dens[t] = fmaxf(dn, EPSV);
  __syncthreads();
  const float inv = 1.0f / dens[t];
  const int n = (c * CHK + t) * B_ + b;
  ushort* op = attn + (size_t)n * E_ + h * D_ + d0;
  #pragma unroll
  for (int j = 0; j < 16; ++j) op[j] = f2b(num[j] * inv);
}

extern "C" void kernel_launch(void* const* d_in, const int* in_sizes, int n_in,
                              void* d_out, int out_size, void* d_ws, size_t ws_size,
                              hipStream_t stream) {
  const float* x  = (const float*)d_in[0];
  const float* rm = (const float*)d_in[1];
  const float* Wq = (const float*)d_in[2];
  const float* bq = (const float*)d_in[3];
  const float* Wk = (const float*)d_in[4];
  const float* bk = (const float*)d_in[5];
  const float* Wv = (const float*)d_in[6];
  const float* bv = (const float*)d_in[7];
  const float* Wo = (const float*)d_in[8];
  const float* bo = (const float*)d_in[9];
  float* out = (float*)d_out;

  float* qf   = (float*)d_ws;                          // [N,E] f32   8 MB
  float* kf   = qf + (size_t)N_ * E_;                  // [N,E] f32   8 MB
  ushort* vb  = (ushort*)(kf + (size_t)N_ * E_);       // [N,E] bf16  4 MB
  ushort* pqb = vb + (size_t)N_ * E_;                  // [N,H,K2]    8 MB
  ushort* pkb = pqb + (size_t)N_ * H_ * K2;            // [N,H,K2]    8 MB
  float* cS   = (float*)(pkb + (size_t)N_ * H_ * K2);  // [NC,BH,K2,D] 16 MB (prefix in-place)
  float* cz   = cS + (size_t)NC * BH * K2 * D_;        // [NC,BH,K2]  0.25 MB
  ushort* attnb = (ushort*)(cz + (size_t)NC * BH * K2);// [N,E] bf16  4 MB

  const dim3 blk(256);
  const dim3 gg(N_ / 64, E_ / 64);
  gemm_bias_kernel<float, float ><<<gg, blk, 0, stream>>>(x, Wq, bq, qf, E_, E_);
  gemm_bias_kernel<float, float ><<<gg, blk, 0, stream>>>(x, Wk, bk, kf, E_, E_);
  gemm_bias_kernel<float, ushort><<<gg, blk, 0, stream>>>(x, Wv, bv, vb, E_, E_);
  phi_kernel<<<dim3(N_ * H_ / 4, 2), blk, 0, stream>>>(qf, kf, rm, pqb, pkb);
  chunk_sum_kernel<<<dim3(NC, BH), blk, 0, stream>>>(pkb, vb, cS, cz);
  prefix_kernel<<<dim3(BH), blk, 0, stream>>>(cS, cz);
  chunk_out_kernel<<<dim3(NC, BH), blk, 0, stream>>>(pqb, pkb, vb, cS, cz, attnb);
  gemm_bias_kernel<ushort, float><<<gg, blk, 0, stream>>>(attnb, Wo, bo, out, E_, E_);
}

// Round 3
// 246.221 us; speedup vs baseline: 1.5940x; 1.5940x over previous
//
#include <hip/hip_runtime.h>

#define T_ 1024
#define B_ 4
#define E_ 512
#define H_ 8
#define D_ 64
#define P_ 64
#define K2 128            // 2P
#define N_ (T_*B_)        // 4096 rows (t*B + b)
#define CHK 64            // scan chunk length
#define NC (T_/CHK)       // 16 chunks
#define BH (B_*H_)        // 32
#define EPSV 1e-6f

typedef unsigned int uint;
typedef unsigned short ushort;
typedef short short8 __attribute__((ext_vector_type(8)));   // 8 bf16 = 4 VGPRs (MFMA A/B frag)
typedef float f32x4 __attribute__((ext_vector_type(4)));    // MFMA C/D frag

__device__ __forceinline__ float b2f(ushort u){ return __uint_as_float(((uint)u) << 16); }
__device__ __forceinline__ ushort f2b(float f){
  uint x = __float_as_uint(f);
  return (ushort)((x + 0x7fffu + ((x >> 16) & 1u)) >> 16);   // RNE
}
__device__ __forceinline__ float lo16(uint u){ return __uint_as_float(u << 16); }
__device__ __forceinline__ float hi16(uint u){ return __uint_as_float(u & 0xffff0000u); }
__device__ __forceinline__ void st(float* p, float v){ *p = v; }
__device__ __forceinline__ void st(ushort* p, float v){ *p = f2b(v); }

// Cast x + 4 weight matrices f32 -> bf16. blockIdx.y selects segment.
__global__ __launch_bounds__(256) void cast_kernel(
    const float* __restrict__ x, const float* __restrict__ wq, const float* __restrict__ wk,
    const float* __restrict__ wv, const float* __restrict__ wo,
    ushort* __restrict__ xb, ushort* __restrict__ wqb, ushort* __restrict__ wkb,
    ushort* __restrict__ wvb, ushort* __restrict__ wob)
{
  const float* src; ushort* dst; int n4;
  switch (blockIdx.y) {
    case 0:  src = x;  dst = xb;  n4 = N_ * E_ / 4; break;
    case 1:  src = wq; dst = wqb; n4 = E_ * E_ / 4; break;
    case 2:  src = wk; dst = wkb; n4 = E_ * E_ / 4; break;
    case 3:  src = wv; dst = wvb; n4 = E_ * E_ / 4; break;
    default: src = wo; dst = wob; n4 = E_ * E_ / 4; break;
  }
  const int stride = gridDim.x * 256;
  for (int i = blockIdx.x * 256 + threadIdx.x; i < n4; i += stride) {
    const float4 v = *(const float4*)(src + (size_t)i * 4);
    ushort4 o; o.x = f2b(v.x); o.y = f2b(v.y); o.z = f2b(v.z); o.w = f2b(v.w);
    *(ushort4*)(dst + (size_t)i * 4) = o;
  }
}

// out[n,m] = sum_e A[n,e]*W[m,e] + bias[m], bf16 inputs via MFMA 16x16x32.
// One wave computes a 32x32 output tile (4 mfma per K-chunk, 2x operand reuse).
// Frag layouts (gfx950): A/B lane: idx=lane&15, k=(lane>>4)*8+j (contig 16B load).
// C/D (verified m89): col=lane&15, row=(lane>>4)*4+reg.
template<typename OutT>
__global__ __launch_bounds__(256) void gemm_mfma_kernel(
    const ushort* __restrict__ A, const ushort* __restrict__ W,
    const float* __restrict__ bias, OutT* __restrict__ out)
{
  const int wave = threadIdx.x >> 6, lane = threadIdx.x & 63;
  const int row0 = (blockIdx.x * 4 + wave) * 32;
  const int col0 = blockIdx.y * 32;
  const int r = lane & 15, kb = lane >> 4;
  const ushort* a0 = A + (size_t)(row0 + r) * E_ + kb * 8;
  const ushort* a1 = a0 + 16 * E_;
  const ushort* b0 = W + (size_t)(col0 + r) * E_ + kb * 8;
  const ushort* b1 = b0 + 16 * E_;
  f32x4 acc00 = {0.f,0.f,0.f,0.f}, acc01 = {0.f,0.f,0.f,0.f};
  f32x4 acc10 = {0.f,0.f,0.f,0.f}, acc11 = {0.f,0.f,0.f,0.f};
  #pragma unroll 4
  for (int k0 = 0; k0 < E_; k0 += 32) {
    const short8 av0 = *(const short8*)(a0 + k0);
    const short8 av1 = *(const short8*)(a1 + k0);
    const short8 bv0 = *(const short8*)(b0 + k0);
    const short8 bv1 = *(const short8*)(b1 + k0);
    acc00 = __builtin_amdgcn_mfma_f32_16x16x32_bf16(av0, bv0, acc00, 0, 0, 0);
    acc01 = __builtin_amdgcn_mfma_f32_16x16x32_bf16(av0, bv1, acc01, 0, 0, 0);
    acc10 = __builtin_amdgcn_mfma_f32_16x16x32_bf16(av1, bv0, acc10, 0, 0, 0);
    acc11 = __builtin_amdgcn_mfma_f32_16x16x32_bf16(av1, bv1, acc11, 0, 0, 0);
  }
  const float bs0 = bias[col0 + r], bs1 = bias[col0 + 16 + r];
  #pragma unroll
  for (int j = 0; j < 4; ++j) {
    const int rr = kb * 4 + j;
    st(out + (size_t)(row0 + rr) * E_ + col0 + r,           acc00[j] + bs0);
    st(out + (size_t)(row0 + rr) * E_ + col0 + 16 + r,      acc01[j] + bs1);
    st(out + (size_t)(row0 + 16 + rr) * E_ + col0 + r,      acc10[j] + bs0);
    st(out + (size_t)(row0 + 16 + rr) * E_ + col0 + 16 + r, acc11[j] + bs1);
  }
}

// phi: block = one h, 4 waves = 4 consecutive n. rm[h] staged in LDS (stride 66:
// 8B-aligned float2 rows, 4-way bank alias only). __sinf/__cosf (v_sin_f32).
__global__ __launch_bounds__(256) void phi_kernel(
    const float* __restrict__ qf, const float* __restrict__ kf,
    const float* __restrict__ rm, ushort* __restrict__ pq, ushort* __restrict__ pk)
{
  __shared__ float s_rm[P_ * 66];
  __shared__ float xs[4][D_];
  const int tid = threadIdx.x, w = tid >> 6, lane = tid & 63;
  const int h = blockIdx.y;
  const float* src = blockIdx.z ? kf : qf;
  ushort* dst = blockIdx.z ? pk : pq;
  const float* rmh = rm + (size_t)h * P_ * D_;
  for (int i = tid; i < P_ * D_; i += 256)
    s_rm[(i >> 6) * 66 + (i & 63)] = rmh[i];
  const int n = blockIdx.x * 4 + w;
  const float val = src[(size_t)n * E_ + h * D_ + lane];
  float s2 = val * val;
  #pragma unroll
  for (int off = 32; off; off >>= 1) s2 += __shfl_xor(s2, off, 64);
  xs[w][lane] = val * (1.0f / fmaxf(sqrtf(s2), EPSV));
  __syncthreads();
  const float* rrow = s_rm + lane * 66;   // lane = p
  float acc = 0.f;
  #pragma unroll
  for (int d0 = 0; d0 < D_; d0 += 2) {
    const float2 rv = *(const float2*)(rrow + d0);
    const float2 xv = *(const float2*)(&xs[w][d0]);
    acc += rv.x * xv.x + rv.y * xv.y;
  }
  const size_t base = ((size_t)n * H_ + h) * K2 + lane;
  dst[base]      = f2b(__sinf(acc) * 0.125f);   // P^-0.5 = 0.125
  dst[base + 64] = f2b(__cosf(acc) * 0.125f);
}

// Per-chunk sums: cS[c,bh,k,d] = sum_{t in chunk} pk[t,k]*v[t,d]; cz likewise.
__global__ __launch_bounds__(256) void chunk_sum_kernel(
    const ushort* __restrict__ pk, const ushort* __restrict__ v,
    float* __restrict__ cS, float* __restrict__ cz)
{
  const int c = blockIdx.x, bh = blockIdx.y, b = bh >> 3, h = bh & 7;
  __shared__ float pks[CHK][K2];
  __shared__ float vsh[CHK][D_];
  const int tid = threadIdx.x;
  for (int i = tid; i < CHK * K2; i += 256) {
    const int tt = i >> 7, k = i & 127;
    const int n = (c * CHK + tt) * B_ + b;
    pks[tt][k] = b2f(pk[((size_t)n * H_ + h) * K2 + k]);
  }
  for (int i = tid; i < CHK * D_; i += 256) {
    const int tt = i >> 6, d = i & 63;
    const int n = (c * CHK + tt) * B_ + b;
    vsh[tt][d] = b2f(v[(size_t)n * E_ + h * D_ + d]);
  }
  __syncthreads();
  const int d = tid & 63, kg = tid >> 6;
  float acc[32] = {};
  for (int tt = 0; tt < CHK; ++tt) {
    const float vv = vsh[tt][d];
    const float4* pk4 = (const float4*)(&pks[tt][kg * 32]);
    #pragma unroll
    for (int i4 = 0; i4 < 8; ++i4) {
      const float4 p = pk4[i4];
      acc[i4*4+0] += p.x * vv; acc[i4*4+1] += p.y * vv;
      acc[i4*4+2] += p.z * vv; acc[i4*4+3] += p.w * vv;
    }
  }
  float* So = cS + (size_t)(c * BH + bh) * (K2 * D_);
  #pragma unroll
  for (int i = 0; i < 32; ++i) So[(kg * 32 + i) * D_ + d] = acc[i];
  if (tid < K2) {
    float zacc = 0.f;
    for (int tt = 0; tt < CHK; ++tt) zacc += pks[tt][tid];
    cz[(size_t)(c * BH + bh) * K2 + tid] = zacc;
  }
}

// In-place exclusive prefix over chunks.
__global__ __launch_bounds__(256) void prefix_kernel(
    float* __restrict__ cS, float* __restrict__ cz)
{
  const int bh = blockIdx.x, tid = threadIdx.x;
  float run[32];
  #pragma unroll
  for (int i = 0; i < 32; ++i) run[i] = 0.f;
  for (int c = 0; c < NC; ++c) {
    float* p = cS + (size_t)(c * BH + bh) * (K2 * D_);
    #pragma unroll
    for (int i = 0; i < 32; ++i) {
      const int e = i * 256 + tid;
      const float t = p[e];
      p[e] = run[i];
      run[i] += t;
    }
  }
  if (tid < K2) {
    float rz = 0.f;
    for (int c = 0; c < NC; ++c) {
      float* pz = cz + (size_t)(c * BH + bh) * K2 + tid;
      const float t = *pz;
      *pz = rz;
      rz += t;
    }
  }
}

// Per-chunk outputs: A = causal(pq@pk^T); attn = (A@v + pq@Sp) / max(rowsum(A)+pq@zp, eps)
__global__ __launch_bounds__(256) void chunk_out_kernel(
    const ushort* __restrict__ pq, const ushort* __restrict__ pkg,
    const ushort* __restrict__ v, const float* __restrict__ Sp,
    const float* __restrict__ zp, ushort* __restrict__ attn)
{
  const int c = blockIdx.x, bh = blockIdx.y, b = bh >> 3, h = bh & 7;
  __shared__ ushort pqs[CHK][K2];
  __shared__ ushort pks[CHK][K2];
  __shared__ ushort vs[CHK][D_];
  __shared__ float Am[CHK][CHK + 2];
  __shared__ float zps[K2];
  __shared__ float dens[CHK];
  const int tid = threadIdx.x;
  for (int i = tid; i < CHK * K2 / 8; i += 256) {
    const int tt = i >> 4, k8 = (i & 15) * 8;
    const int n = (c * CHK + tt) * B_ + b;
    const size_t off = ((size_t)n * H_ + h) * K2 + k8;
    *(uint4*)(&pqs[tt][k8]) = *(const uint4*)(pq + off);
    *(uint4*)(&pks[tt][k8]) = *(const uint4*)(pkg + off);
  }
  for (int i = tid; i < CHK * D_ / 8; i += 256) {
    const int tt = i >> 3, d8 = (i & 7) * 8;
    const int n = (c * CHK + tt) * B_ + b;
    *(uint4*)(&vs[tt][d8]) = *(const uint4*)(v + (size_t)n * E_ + h * D_ + d8);
  }
  if (tid < K2) zps[tid] = zp[(size_t)(c * BH + bh) * K2 + tid];
  __syncthreads();
  const int t = tid >> 2;
  {
    const int tg = tid & 3;
    float accA[16] = {};
    for (int k0 = 0; k0 < K2; k0 += 8) {
      const uint4 uq = *(const uint4*)(&pqs[t][k0]);
      const float p0 = lo16(uq.x), p1 = hi16(uq.x), p2 = lo16(uq.y), p3 = hi16(uq.y);
      const float p4 = lo16(uq.z), p5 = hi16(uq.z), p6 = lo16(uq.w), p7 = hi16(uq.w);
      #pragma unroll
      for (int j = 0; j < 16; ++j) {
        const uint4 uk = *(const uint4*)(&pks[tg * 16 + j][k0]);
        accA[j] += p0*lo16(uk.x) + p1*hi16(uk.x) + p2*lo16(uk.y) + p3*hi16(uk.y)
                 + p4*lo16(uk.z) + p5*hi16(uk.z) + p6*lo16(uk.w) + p7*hi16(uk.w);
      }
    }
    #pragma unroll
    for (int j = 0; j < 16; ++j) {
      const int tau = tg * 16 + j;
      Am[t][tau] = (tau <= t) ? accA[j] : 0.f;
    }
  }
  __syncthreads();
  const int dg = tid & 3, d0 = dg * 16;
  float num[16] = {};
  float dn = 0.f;
  for (int tau = 0; tau < CHK; ++tau) {
    const float a = Am[t][tau];
    dn += a;
    const uint4 u0 = *(const uint4*)(&vs[tau][d0]);
    const uint4 u1 = *(const uint4*)(&vs[tau][d0 + 8]);
    num[0]  += a*lo16(u0.x); num[1]  += a*hi16(u0.x);
    num[2]  += a*lo16(u0.y); num[3]  += a*hi16(u0.y);
    num[4]  += a*lo16(u0.z); num[5]  += a*hi16(u0.z);
    num[6]  += a*lo16(u0.w); num[7]  += a*hi16(u0.w);
    num[8]  += a*lo16(u1.x); num[9]  += a*hi16(u1.x);
    num[10] += a*lo16(u1.y); num[11] += a*hi16(u1.y);
    num[12] += a*lo16(u1.z); num[13] += a*hi16(u1.z);
    num[14] += a*lo16(u1.w); num[15] += a*hi16(u1.w);
  }
  const float* Srow = Sp + (size_t)(c * BH + bh) * (K2 * D_) + d0;
  for (int k = 0; k < K2; ++k) {
    const float pqv = b2f(pqs[t][k]);
    dn += pqv * zps[k];
    const float4 s0 = *(const float4*)(Srow + k * D_ + 0);
    const float4 s1 = *(const float4*)(Srow + k * D_ + 4);
    const float4 s2 = *(const float4*)(Srow + k * D_ + 8);
    const float4 s3 = *(const float4*)(Srow + k * D_ + 12);
    num[0]  += pqv*s0.x; num[1]  += pqv*s0.y; num[2]  += pqv*s0.z; num[3]  += pqv*s0.w;
    num[4]  += pqv*s1.x; num[5]  += pqv*s1.y; num[6]  += pqv*s1.z; num[7]  += pqv*s1.w;
    num[8]  += pqv*s2.x; num[9]  += pqv*s2.y; num[10] += pqv*s2.z; num[11] += pqv*s2.w;
    num[12] += pqv*s3.x; num[13] += pqv*s3.y; num[14] += pqv*s3.z; num[15] += pqv*s3.w;
  }
  if (dg == 0) dens[t] = fmaxf(dn, EPSV);
  __syncthreads();
  const float inv = 1.0f / dens[t];
  const int n = (c * CHK + t) * B_ + b;
  ushort* op = attn + (size_t)n * E_ + h * D_ + d0;
  #pragma unroll
  for (int j = 0; j < 16; ++j) op[j] = f2b(num[j] * inv);
}

extern "C" void kernel_launch(void* const* d_in, const int* in_sizes, int n_in,
                              void* d_out, int out_size, void* d_ws, size_t ws_size,
                              hipStream_t stream) {
  const float* x  = (const float*)d_in[0];
  const float* rm = (const float*)d_in[1];
  const float* Wq = (const float*)d_in[2];
  const float* bq = (const float*)d_in[3];
  const float* Wk = (const float*)d_in[4];
  const float* bk = (const float*)d_in[5];
  const float* Wv = (const float*)d_in[6];
  const float* bv = (const float*)d_in[7];
  const float* Wo = (const float*)d_in[8];
  const float* bo = (const float*)d_in[9];
  float* out = (float*)d_out;

  // ws layout (42.25 MB) with lifetime aliasing:
  float* qf = (float*)d_ws;                       // [N,E] f32, dead after phi
  float* kf = qf + (size_t)N_ * E_;               // [N,E] f32, dead after phi
  float* cS = qf;                                 // [NC,BH,K2,D] f32 — ALIASES qf+kf (16MB)
  ushort* vb  = (ushort*)(kf + (size_t)N_ * E_);  // [N,E] bf16
  ushort* pqb = vb + (size_t)N_ * E_;             // [N,H,K2] bf16
  ushort* pkb = pqb + (size_t)N_ * H_ * K2;       // [N,H,K2] bf16
  float* cz = (float*)(pkb + (size_t)N_ * H_ * K2);   // [NC,BH,K2] f32
  ushort* xb = (ushort*)(cz + (size_t)NC * BH * K2);  // [N,E] bf16, dead after QKV gemms
  ushort* attnb = xb;                             // [N,E] bf16 — ALIASES xb
  ushort* wqb = xb + (size_t)N_ * E_;             // [E,E] bf16
  ushort* wkb = wqb + (size_t)E_ * E_;
  ushort* wvb = wkb + (size_t)E_ * E_;
  ushort* wob = wvb + (size_t)E_ * E_;

  const dim3 blk(256);
  cast_kernel<<<dim3(512, 5), blk, 0, stream>>>(x, Wq, Wk, Wv, Wo, xb, wqb, wkb, wvb, wob);
  const dim3 gg(N_ / 128, E_ / 32);
  gemm_mfma_kernel<float ><<<gg, blk, 0, stream>>>(xb, wqb, bq, qf);
  gemm_mfma_kernel<float ><<<gg, blk, 0, stream>>>(xb, wkb, bk, kf);
  gemm_mfma_kernel<ushort><<<gg, blk, 0, stream>>>(xb, wvb, bv, vb);
  phi_kernel<<<dim3(N_ / 4, H_, 2), blk, 0, stream>>>(qf, kf, rm, pqb, pkb);
  chunk_sum_kernel<<<dim3(NC, BH), blk, 0, stream>>>(pkb, vb, cS, cz);
  prefix_kernel<<<dim3(BH), blk, 0, stream>>>(cS, cz);
  chunk_out_kernel<<<dim3(NC, BH), blk, 0, stream>>>(pqb, pkb, vb, cS, cz, attnb);
  gemm_mfma_kernel<float ><<<gg, blk, 0, stream>>>(attnb, wob, bo, out);
}

// Round 4
// 145.174 us; speedup vs baseline: 2.7035x; 1.6960x over previous
//
#include <hip/hip_runtime.h>

#define T_ 1024
#define B_ 4
#define E_ 512
#define H_ 8
#define D_ 64
#define P_ 64
#define K2 128            // 2P
#define N_ (T_*B_)        // 4096 rows (t*B + b)
#define CHK 64            // scan chunk length
#define NC (T_/CHK)       // 16 chunks
#define BH (B_*H_)        // 32
#define EPSV 1e-6f

typedef unsigned int uint;
typedef unsigned short ushort;
typedef short short8 __attribute__((ext_vector_type(8)));   // 8 bf16 (MFMA A/B frag)
typedef float f32x4 __attribute__((ext_vector_type(4)));    // MFMA C/D frag

__device__ __forceinline__ float b2f(ushort u){ return __uint_as_float(((uint)u) << 16); }
__device__ __forceinline__ ushort f2b(float f){
  uint x = __float_as_uint(f);
  return (ushort)((x + 0x7fffu + ((x >> 16) & 1u)) >> 16);   // RNE
}
__device__ __forceinline__ float lo16(uint u){ return __uint_as_float(u << 16); }
__device__ __forceinline__ float hi16(uint u){ return __uint_as_float(u & 0xffff0000u); }
__device__ __forceinline__ void st(float* p, float v){ *p = v; }
__device__ __forceinline__ void st(ushort* p, float v){ *p = f2b(v); }

// ---------------- cast f32 -> bf16 (x + 4 weights) ----------------
__global__ __launch_bounds__(256) void cast_kernel(
    const float* __restrict__ x, const float* __restrict__ wq, const float* __restrict__ wk,
    const float* __restrict__ wv, const float* __restrict__ wo,
    ushort* __restrict__ xb, ushort* __restrict__ wqb, ushort* __restrict__ wkb,
    ushort* __restrict__ wvb, ushort* __restrict__ wob)
{
  const float* src; ushort* dst; int n4;
  switch (blockIdx.y) {
    case 0:  src = x;  dst = xb;  n4 = N_ * E_ / 4; break;
    case 1:  src = wq; dst = wqb; n4 = E_ * E_ / 4; break;
    case 2:  src = wk; dst = wkb; n4 = E_ * E_ / 4; break;
    case 3:  src = wv; dst = wvb; n4 = E_ * E_ / 4; break;
    default: src = wo; dst = wob; n4 = E_ * E_ / 4; break;
  }
  const int stride = gridDim.x * 256;
  for (int i = blockIdx.x * 256 + threadIdx.x; i < n4; i += stride) {
    const float4 v = *(const float4*)(src + (size_t)i * 4);
    ushort4 o; o.x = f2b(v.x); o.y = f2b(v.y); o.z = f2b(v.z); o.w = f2b(v.w);
    *(ushort4*)(dst + (size_t)i * 4) = o;
  }
}

// ---------------- fused QKV GEMM (MFMA, 32x32 tile per wave) ----------------
// blockIdx.z: 0->q(f32) 1->k(f32) 2->v(bf16)
__global__ __launch_bounds__(256) void gemm_qkv_kernel(
    const ushort* __restrict__ A,
    const ushort* __restrict__ wq, const ushort* __restrict__ wk, const ushort* __restrict__ wv,
    const float* __restrict__ bq, const float* __restrict__ bk, const float* __restrict__ bv,
    float* __restrict__ qf, float* __restrict__ kf, ushort* __restrict__ vb)
{
  const ushort* W; const float* bias;
  const int z = blockIdx.z;
  if (z == 0) { W = wq; bias = bq; }
  else if (z == 1) { W = wk; bias = bk; }
  else { W = wv; bias = bv; }
  const int wave = threadIdx.x >> 6, lane = threadIdx.x & 63;
  const int row0 = (blockIdx.x * 4 + wave) * 32;
  const int col0 = blockIdx.y * 32;
  const int r = lane & 15, kb = lane >> 4;
  const ushort* a0 = A + (size_t)(row0 + r) * E_ + kb * 8;
  const ushort* a1 = a0 + 16 * E_;
  const ushort* b0 = W + (size_t)(col0 + r) * E_ + kb * 8;
  const ushort* b1 = b0 + 16 * E_;
  f32x4 acc00 = {0.f,0.f,0.f,0.f}, acc01 = {0.f,0.f,0.f,0.f};
  f32x4 acc10 = {0.f,0.f,0.f,0.f}, acc11 = {0.f,0.f,0.f,0.f};
  #pragma unroll 4
  for (int k0 = 0; k0 < E_; k0 += 32) {
    const short8 av0 = *(const short8*)(a0 + k0);
    const short8 av1 = *(const short8*)(a1 + k0);
    const short8 bv0 = *(const short8*)(b0 + k0);
    const short8 bv1 = *(const short8*)(b1 + k0);
    acc00 = __builtin_amdgcn_mfma_f32_16x16x32_bf16(av0, bv0, acc00, 0, 0, 0);
    acc01 = __builtin_amdgcn_mfma_f32_16x16x32_bf16(av0, bv1, acc01, 0, 0, 0);
    acc10 = __builtin_amdgcn_mfma_f32_16x16x32_bf16(av1, bv0, acc10, 0, 0, 0);
    acc11 = __builtin_amdgcn_mfma_f32_16x16x32_bf16(av1, bv1, acc11, 0, 0, 0);
  }
  const float bs0 = bias[col0 + r], bs1 = bias[col0 + 16 + r];
  float* of = (z == 0) ? qf : kf;
  #pragma unroll
  for (int j = 0; j < 4; ++j) {
    const int rr = kb * 4 + j;
    if (z == 2) {
      vb[(size_t)(row0 + rr) * E_ + col0 + r]           = f2b(acc00[j] + bs0);
      vb[(size_t)(row0 + rr) * E_ + col0 + 16 + r]      = f2b(acc01[j] + bs1);
      vb[(size_t)(row0 + 16 + rr) * E_ + col0 + r]      = f2b(acc10[j] + bs0);
      vb[(size_t)(row0 + 16 + rr) * E_ + col0 + 16 + r] = f2b(acc11[j] + bs1);
    } else {
      of[(size_t)(row0 + rr) * E_ + col0 + r]           = acc00[j] + bs0;
      of[(size_t)(row0 + rr) * E_ + col0 + 16 + r]      = acc01[j] + bs1;
      of[(size_t)(row0 + 16 + rr) * E_ + col0 + r]      = acc10[j] + bs0;
      of[(size_t)(row0 + 16 + rr) * E_ + col0 + 16 + r] = acc11[j] + bs1;
    }
  }
}

// ---------------- output GEMM (MFMA) ----------------
__global__ __launch_bounds__(256) void gemm_out_kernel(
    const ushort* __restrict__ A, const ushort* __restrict__ W,
    const float* __restrict__ bias, float* __restrict__ out)
{
  const int wave = threadIdx.x >> 6, lane = threadIdx.x & 63;
  const int row0 = (blockIdx.x * 4 + wave) * 32;
  const int col0 = blockIdx.y * 32;
  const int r = lane & 15, kb = lane >> 4;
  const ushort* a0 = A + (size_t)(row0 + r) * E_ + kb * 8;
  const ushort* a1 = a0 + 16 * E_;
  const ushort* b0 = W + (size_t)(col0 + r) * E_ + kb * 8;
  const ushort* b1 = b0 + 16 * E_;
  f32x4 acc00 = {0.f,0.f,0.f,0.f}, acc01 = {0.f,0.f,0.f,0.f};
  f32x4 acc10 = {0.f,0.f,0.f,0.f}, acc11 = {0.f,0.f,0.f,0.f};
  #pragma unroll 4
  for (int k0 = 0; k0 < E_; k0 += 32) {
    const short8 av0 = *(const short8*)(a0 + k0);
    const short8 av1 = *(const short8*)(a1 + k0);
    const short8 bv0 = *(const short8*)(b0 + k0);
    const short8 bv1 = *(const short8*)(b1 + k0);
    acc00 = __builtin_amdgcn_mfma_f32_16x16x32_bf16(av0, bv0, acc00, 0, 0, 0);
    acc01 = __builtin_amdgcn_mfma_f32_16x16x32_bf16(av0, bv1, acc01, 0, 0, 0);
    acc10 = __builtin_amdgcn_mfma_f32_16x16x32_bf16(av1, bv0, acc10, 0, 0, 0);
    acc11 = __builtin_amdgcn_mfma_f32_16x16x32_bf16(av1, bv1, acc11, 0, 0, 0);
  }
  const float bs0 = bias[col0 + r], bs1 = bias[col0 + 16 + r];
  #pragma unroll
  for (int j = 0; j < 4; ++j) {
    const int rr = kb * 4 + j;
    out[(size_t)(row0 + rr) * E_ + col0 + r]           = acc00[j] + bs0;
    out[(size_t)(row0 + rr) * E_ + col0 + 16 + r]      = acc01[j] + bs1;
    out[(size_t)(row0 + 16 + rr) * E_ + col0 + r]      = acc10[j] + bs0;
    out[(size_t)(row0 + 16 + rr) * E_ + col0 + 16 + r] = acc11[j] + bs1;
  }
}

// ---------------- phi ----------------
__global__ __launch_bounds__(256) void phi_kernel(
    const float* __restrict__ qf, const float* __restrict__ kf,
    const float* __restrict__ rm, ushort* __restrict__ pq, ushort* __restrict__ pk)
{
  __shared__ float s_rm[P_ * 66];
  __shared__ float xs[4][D_];
  const int tid = threadIdx.x, w = tid >> 6, lane = tid & 63;
  const int h = blockIdx.y;
  const float* src = blockIdx.z ? kf : qf;
  ushort* dst = blockIdx.z ? pk : pq;
  const float* rmh = rm + (size_t)h * P_ * D_;
  for (int i = tid; i < P_ * D_; i += 256)
    s_rm[(i >> 6) * 66 + (i & 63)] = rmh[i];
  const int n = blockIdx.x * 4 + w;
  const float val = src[(size_t)n * E_ + h * D_ + lane];
  float s2 = val * val;
  #pragma unroll
  for (int off = 32; off; off >>= 1) s2 += __shfl_xor(s2, off, 64);
  xs[w][lane] = val * (1.0f / fmaxf(sqrtf(s2), EPSV));
  __syncthreads();
  const float* rrow = s_rm + lane * 66;   // lane = p
  float acc = 0.f;
  #pragma unroll
  for (int d0 = 0; d0 < D_; d0 += 2) {
    const float2 rv = *(const float2*)(rrow + d0);
    const float2 xv = *(const float2*)(&xs[w][d0]);
    acc += rv.x * xv.x + rv.y * xv.y;
  }
  const size_t base = ((size_t)n * H_ + h) * K2 + lane;
  dst[base]      = f2b(__sinf(acc) * 0.125f);   // P^-0.5
  dst[base + 64] = f2b(__cosf(acc) * 0.125f);
}

// ---------------- chunk_sum via MFMA: cS[k2][d] = sum_tau pk[tau][k2]*v[tau][d] ----------------
__global__ __launch_bounds__(256) void chunk_sum_kernel(
    const ushort* __restrict__ pk, const ushort* __restrict__ v,
    float* __restrict__ cS, float* __restrict__ cz)
{
  const int c = blockIdx.x, bh = blockIdx.y, b = bh >> 3, h = bh & 7;
  __shared__ ushort pkT[K2][88];   // [k2][tau], row 176B: 16B-aligned, 2-way banks
  __shared__ ushort vT[D_][88];    // [d][tau]
  const int tid = threadIdx.x;
  for (int i = tid; i < CHK * 16; i += 256) {            // pk: coalesced read, transposed write
    const int tt = i >> 4, k8 = (i & 15) * 8;
    const int n = (c * CHK + tt) * B_ + b;
    const ushort4 u0 = *(const ushort4*)(pk + ((size_t)n * H_ + h) * K2 + k8);
    const ushort4 u1 = *(const ushort4*)(pk + ((size_t)n * H_ + h) * K2 + k8 + 4);
    pkT[k8+0][tt] = u0.x; pkT[k8+1][tt] = u0.y; pkT[k8+2][tt] = u0.z; pkT[k8+3][tt] = u0.w;
    pkT[k8+4][tt] = u1.x; pkT[k8+5][tt] = u1.y; pkT[k8+6][tt] = u1.z; pkT[k8+7][tt] = u1.w;
  }
  for (int i = tid; i < CHK * 16; i += 256) {            // v: transposed
    const int tt = i >> 4, d4 = (i & 15) * 4;
    const int n = (c * CHK + tt) * B_ + b;
    const ushort4 u = *(const ushort4*)(v + (size_t)n * E_ + h * D_ + d4);
    vT[d4+0][tt] = u.x; vT[d4+1][tt] = u.y; vT[d4+2][tt] = u.z; vT[d4+3][tt] = u.w;
  }
  __syncthreads();
  const int w = tid >> 6, lane = tid & 63;
  const int r = lane & 15, kb = lane >> 4;
  const int m0 = w * 32;
  f32x4 acc[2][4] = {};
  #pragma unroll
  for (int k0 = 0; k0 < CHK; k0 += 32) {
    const short8 a0 = *(const short8*)(&pkT[m0 + r][k0 + kb * 8]);
    const short8 a1 = *(const short8*)(&pkT[m0 + 16 + r][k0 + kb * 8]);
    #pragma unroll
    for (int nt = 0; nt < 4; ++nt) {
      const short8 bv = *(const short8*)(&vT[nt * 16 + r][k0 + kb * 8]);
      acc[0][nt] = __builtin_amdgcn_mfma_f32_16x16x32_bf16(a0, bv, acc[0][nt], 0, 0, 0);
      acc[1][nt] = __builtin_amdgcn_mfma_f32_16x16x32_bf16(a1, bv, acc[1][nt], 0, 0, 0);
    }
  }
  float* So = cS + (size_t)(c * BH + bh) * (K2 * D_);
  #pragma unroll
  for (int mt = 0; mt < 2; ++mt)
    #pragma unroll
    for (int nt = 0; nt < 4; ++nt)
      #pragma unroll
      for (int j = 0; j < 4; ++j)
        So[(m0 + mt * 16 + kb * 4 + j) * D_ + nt * 16 + r] = acc[mt][nt][j];
  if (tid < K2) {
    float zacc = 0.f;
    #pragma unroll
    for (int i2 = 0; i2 < CHK / 2; ++i2) {
      const uint u = *(const uint*)(&pkT[tid][i2 * 2]);
      zacc += lo16(u) + hi16(u);
    }
    cz[(size_t)(c * BH + bh) * K2 + tid] = zacc;
  }
}

// ---------------- exclusive prefix over chunks (coalesced, 1 elem/thread) ----------------
__global__ __launch_bounds__(256) void prefix_kernel(
    float* __restrict__ cS, float* __restrict__ cz)
{
  const int gid = blockIdx.x * 256 + threadIdx.x;   // 262144 threads
  const int bh = gid >> 13, rem = gid & 8191;
  float run = 0.f;
  #pragma unroll
  for (int c = 0; c < NC; ++c) {
    float* p = cS + (((size_t)(c * BH + bh)) << 13) + rem;
    const float t = *p; *p = run; run += t;
  }
  if (gid < BH * K2) {
    const int zbh = gid >> 7, k2 = gid & 127;
    float rz = 0.f;
    #pragma unroll
    for (int c = 0; c < NC; ++c) {
      float* pz = cz + (size_t)(c * BH + zbh) * K2 + k2;
      const float t = *pz; *pz = rz; rz += t;
    }
  }
}

// ---------------- chunk_out via MFMA ----------------
// A = causal(pq@pk^T); attn = (A@v + pq@Sp) / max(rowsum(A)+pq@zp, eps)
__global__ __launch_bounds__(256) void chunk_out_kernel(
    const ushort* __restrict__ pq, const ushort* __restrict__ pkg,
    const ushort* __restrict__ v, const float* __restrict__ Sp,
    const float* __restrict__ zp, ushort* __restrict__ attn)
{
  const int c = blockIdx.x, bh = blockIdx.y, b = bh >> 3, h = bh & 7;
  __shared__ ushort pq_s[CHK][136];   // 272B rows: 16B-aligned, 2-way banks
  __shared__ ushort pk_s[CHK][136];
  __shared__ ushort SpT_s[D_][136];   // [d][k2] bf16
  __shared__ ushort vT_s[D_][88];     // [d][tau]
  __shared__ ushort Am_s[CHK][88];    // masked A bf16 [t][tau]
  __shared__ float zps[K2];
  __shared__ float dens_s[CHK];
  __shared__ float inv_s[CHK];
  const int tid = threadIdx.x;
  for (int i = tid; i < CHK * 16; i += 256) {
    const int tt = i >> 4, k8 = (i & 15) * 8;
    const int n = (c * CHK + tt) * B_ + b;
    const size_t off = ((size_t)n * H_ + h) * K2 + k8;
    *(uint4*)(&pq_s[tt][k8]) = *(const uint4*)(pq + off);
    *(uint4*)(&pk_s[tt][k8]) = *(const uint4*)(pkg + off);
  }
  for (int i = tid; i < CHK * 16; i += 256) {
    const int tt = i >> 4, d4 = (i & 15) * 4;
    const int n = (c * CHK + tt) * B_ + b;
    const ushort4 u = *(const ushort4*)(v + (size_t)n * E_ + h * D_ + d4);
    vT_s[d4+0][tt] = u.x; vT_s[d4+1][tt] = u.y; vT_s[d4+2][tt] = u.z; vT_s[d4+3][tt] = u.w;
  }
  const float* Spb = Sp + (size_t)(c * BH + bh) * (K2 * D_);
  for (int i = tid; i < K2 * 16; i += 256) {
    const int k2 = i >> 4, d4 = (i & 15) * 4;
    const float4 s = *(const float4*)(Spb + k2 * D_ + d4);
    SpT_s[d4+0][k2] = f2b(s.x); SpT_s[d4+1][k2] = f2b(s.y);
    SpT_s[d4+2][k2] = f2b(s.z); SpT_s[d4+3][k2] = f2b(s.w);
  }
  if (tid < K2) zps[tid] = zp[(size_t)(c * BH + bh) * K2 + tid];
  __syncthreads();

  const int w = tid >> 6, lane = tid & 63;
  const int r = lane & 15, kb = lane >> 4;
  const int m0 = w * 16;                 // wave's 16 output rows
  // ---- QK^T ----
  f32x4 accA[4] = {};
  #pragma unroll
  for (int k0 = 0; k0 < K2; k0 += 32) {
    const short8 aq = *(const short8*)(&pq_s[m0 + r][k0 + kb * 8]);
    #pragma unroll
    for (int nt = 0; nt < 4; ++nt) {
      const short8 bk = *(const short8*)(&pk_s[nt * 16 + r][k0 + kb * 8]);
      accA[nt] = __builtin_amdgcn_mfma_f32_16x16x32_bf16(aq, bk, accA[nt], 0, 0, 0);
    }
  }
  // ---- mask + rowsum + Am -> LDS (bf16) ----
  float rs[4] = {0.f, 0.f, 0.f, 0.f};
  #pragma unroll
  for (int nt = 0; nt < 4; ++nt) {
    #pragma unroll
    for (int j = 0; j < 4; ++j) {
      const int row = kb * 4 + j, col = nt * 16 + r;   // chunk-local
      float a = accA[nt][j];
      a = (col <= m0 + row) ? a : 0.f;
      rs[j] += a;
      Am_s[m0 + row][col] = f2b(a);
    }
  }
  #pragma unroll
  for (int off = 1; off < 16; off <<= 1) {
    rs[0] += __shfl_xor(rs[0], off, 64);
    rs[1] += __shfl_xor(rs[1], off, 64);
    rs[2] += __shfl_xor(rs[2], off, 64);
    rs[3] += __shfl_xor(rs[3], off, 64);
  }
  if (r == 0) {
    #pragma unroll
    for (int j = 0; j < 4; ++j) dens_s[m0 + kb * 4 + j] = rs[j];
  }
  // ---- numerator: Am@v + pq@Sp (same accumulators) ----
  f32x4 accO[4] = {};
  #pragma unroll
  for (int k0 = 0; k0 < CHK; k0 += 32) {
    const short8 aa = *(const short8*)(&Am_s[m0 + r][k0 + kb * 8]);
    #pragma unroll
    for (int nt = 0; nt < 4; ++nt) {
      const short8 bv = *(const short8*)(&vT_s[nt * 16 + r][k0 + kb * 8]);
      accO[nt] = __builtin_amdgcn_mfma_f32_16x16x32_bf16(aa, bv, accO[nt], 0, 0, 0);
    }
  }
  #pragma unroll
  for (int k0 = 0; k0 < K2; k0 += 32) {
    const short8 aq = *(const short8*)(&pq_s[m0 + r][k0 + kb * 8]);
    #pragma unroll
    for (int nt = 0; nt < 4; ++nt) {
      const short8 bs = *(const short8*)(&SpT_s[nt * 16 + r][k0 + kb * 8]);
      accO[nt] = __builtin_amdgcn_mfma_f32_16x16x32_bf16(aq, bs, accO[nt], 0, 0, 0);
    }
  }
  // ---- denominator: dens + pq.zp ----
  {
    const int t_loc = m0 + (lane >> 2), seg = lane & 3;
    float qz = 0.f;
    #pragma unroll
    for (int ii = 0; ii < 16; ++ii) {
      const uint u = *(const uint*)(&pq_s[t_loc][seg * 32 + ii * 2]);
      qz += lo16(u) * zps[seg * 32 + ii * 2] + hi16(u) * zps[seg * 32 + ii * 2 + 1];
    }
    qz += __shfl_xor(qz, 1, 64);
    qz += __shfl_xor(qz, 2, 64);
    if (seg == 0) inv_s[t_loc] = 1.0f / fmaxf(dens_s[t_loc] + qz, EPSV);
  }
  // ---- epilogue ----
  #pragma unroll
  for (int j = 0; j < 4; ++j) {
    const int row = m0 + kb * 4 + j;
    const float inv = inv_s[row];
    const int n = (c * CHK + row) * B_ + b;
    ushort* op = attn + (size_t)n * E_ + h * D_;
    #pragma unroll
    for (int nt = 0; nt < 4; ++nt) op[nt * 16 + r] = f2b(accO[nt][j] * inv);
  }
}

extern "C" void kernel_launch(void* const* d_in, const int* in_sizes, int n_in,
                              void* d_out, int out_size, void* d_ws, size_t ws_size,
                              hipStream_t stream) {
  const float* x  = (const float*)d_in[0];
  const float* rm = (const float*)d_in[1];
  const float* Wq = (const float*)d_in[2];
  const float* bq = (const float*)d_in[3];
  const float* Wk = (const float*)d_in[4];
  const float* bk = (const float*)d_in[5];
  const float* Wv = (const float*)d_in[6];
  const float* bv = (const float*)d_in[7];
  const float* Wo = (const float*)d_in[8];
  const float* bo = (const float*)d_in[9];
  float* out = (float*)d_out;

  // ws layout with lifetime aliasing:
  float* qf = (float*)d_ws;                       // [N,E] f32, dead after phi
  float* kf = qf + (size_t)N_ * E_;               // [N,E] f32, dead after phi
  float* cS = qf;                                 // [NC,BH,K2,D] f32 — ALIASES qf+kf
  ushort* vb  = (ushort*)(kf + (size_t)N_ * E_);  // [N,E] bf16
  ushort* pqb = vb + (size_t)N_ * E_;             // [N,H,K2] bf16
  ushort* pkb = pqb + (size_t)N_ * H_ * K2;       // [N,H,K2] bf16
  float* cz = (float*)(pkb + (size_t)N_ * H_ * K2);   // [NC,BH,K2] f32
  ushort* xb = (ushort*)(cz + (size_t)NC * BH * K2);  // [N,E] bf16, dead after QKV gemms
  ushort* attnb = xb;                             // [N,E] bf16 — ALIASES xb
  ushort* wqb = xb + (size_t)N_ * E_;             // [E,E] bf16
  ushort* wkb = wqb + (size_t)E_ * E_;
  ushort* wvb = wkb + (size_t)E_ * E_;
  ushort* wob = wvb + (size_t)E_ * E_;

  const dim3 blk(256);
  cast_kernel<<<dim3(512, 5), blk, 0, stream>>>(x, Wq, Wk, Wv, Wo, xb, wqb, wkb, wvb, wob);
  gemm_qkv_kernel<<<dim3(N_ / 128, E_ / 32, 3), blk, 0, stream>>>(
      xb, wqb, wkb, wvb, bq, bk, bv, qf, kf, vb);
  phi_kernel<<<dim3(N_ / 4, H_, 2), blk, 0, stream>>>(qf, kf, rm, pqb, pkb);
  chunk_sum_kernel<<<dim3(NC, BH), blk, 0, stream>>>(pkb, vb, cS, cz);
  prefix_kernel<<<dim3(1024), blk, 0, stream>>>(cS, cz);
  chunk_out_kernel<<<dim3(NC, BH), blk, 0, stream>>>(pqb, pkb, vb, cS, cz, attnb);
  gemm_out_kernel<<<dim3(N_ / 128, E_ / 32), blk, 0, stream>>>(attnb, wob, bo, out);
}

// Round 5
// 101.911 us; speedup vs baseline: 3.8512x; 1.4245x over previous
//
#include <hip/hip_runtime.h>

#define T_ 1024
#define B_ 4
#define E_ 512
#define H_ 8
#define D_ 64
#define P_ 64
#define K2 128            // 2P
#define N_ (T_*B_)        // 4096 rows (t*B + b)
#define CHK 64            // scan chunk length
#define NC (T_/CHK)       // 16 chunks
#define BH (B_*H_)        // 32
#define EPSV 1e-6f

typedef unsigned int uint;
typedef unsigned short ushort;
typedef short short8 __attribute__((ext_vector_type(8)));   // 8 bf16 (MFMA A/B frag)
typedef float f32x4 __attribute__((ext_vector_type(4)));    // MFMA C/D frag

__device__ __forceinline__ float b2f(ushort u){ return __uint_as_float(((uint)u) << 16); }
__device__ __forceinline__ ushort f2b(float f){
  uint x = __float_as_uint(f);
  return (ushort)((x + 0x7fffu + ((x >> 16) & 1u)) >> 16);   // RNE
}
__device__ __forceinline__ float lo16(uint u){ return __uint_as_float(u << 16); }
__device__ __forceinline__ float hi16(uint u){ return __uint_as_float(u & 0xffff0000u); }
__device__ __forceinline__ void st(float* p, float v){ *p = v; }
__device__ __forceinline__ void st(ushort* p, float v){ *p = f2b(v); }

// async global->LDS, 16B per lane; LDS dest = wave-uniform base + lane*16 (m104)
__device__ __forceinline__ void gl16(const ushort* g, ushort* lds) {
  __builtin_amdgcn_global_load_lds(
      (const __attribute__((address_space(1))) uint*)g,
      (__attribute__((address_space(3))) uint*)lds, 16, 0, 0);
}

// ---------------- cast f32 -> bf16 (x + 4 weights) ----------------
__global__ __launch_bounds__(256) void cast_kernel(
    const float* __restrict__ x, const float* __restrict__ wq, const float* __restrict__ wk,
    const float* __restrict__ wv, const float* __restrict__ wo,
    ushort* __restrict__ xb, ushort* __restrict__ wqb, ushort* __restrict__ wkb,
    ushort* __restrict__ wvb, ushort* __restrict__ wob)
{
  const float* src; ushort* dst; int n4;
  switch (blockIdx.y) {
    case 0:  src = x;  dst = xb;  n4 = N_ * E_ / 4; break;
    case 1:  src = wq; dst = wqb; n4 = E_ * E_ / 4; break;
    case 2:  src = wk; dst = wkb; n4 = E_ * E_ / 4; break;
    case 3:  src = wv; dst = wvb; n4 = E_ * E_ / 4; break;
    default: src = wo; dst = wob; n4 = E_ * E_ / 4; break;
  }
  const int stride = gridDim.x * 256;
  for (int i = blockIdx.x * 256 + threadIdx.x; i < n4; i += stride) {
    const float4 v = *(const float4*)(src + (size_t)i * 4);
    ushort4 o; o.x = f2b(v.x); o.y = f2b(v.y); o.z = f2b(v.z); o.w = f2b(v.w);
    *(ushort4*)(dst + (size_t)i * 4) = o;
  }
}

// ---------------- LDS-staged MFMA GEMM tile: 128x64, BK=32, 2 waves ----------------
// out[n,m] = sum_e A[n,e]*W[m,e] + bias[m]. Per wave: 64x64 out = 16 MFMA + 8 ds_read_b128
// per K-step; staging via global_load_lds width=16 into linear LDS (no padding).
template<typename OutT>
__device__ __forceinline__ void gemm_tile(
    const ushort* __restrict__ A, const ushort* __restrict__ W,
    const float* __restrict__ bias, OutT* __restrict__ out,
    const int row0, const int col0)
{
  __shared__ ushort sA[128 * 32];   // [row][k] rows of 64B, linear
  __shared__ ushort sB[64 * 32];
  const int tid = threadIdx.x, w = tid >> 6, lane = tid & 63;
  const int lrow = lane >> 2, lk8 = (lane & 3) * 8;
  // staging bases: wave w, issue s covers rows s*32 + w*16 + lrow
  const ushort* gA = A + (size_t)(row0 + w * 16 + lrow) * E_ + lk8;
  const ushort* gB = W + (size_t)(col0 + w * 16 + lrow) * E_ + lk8;
  ushort* lA = sA + w * 512;        // + s*1024 elements per issue
  ushort* lB = sB + w * 512;
  const int r = lane & 15, kg = lane >> 4, kq = kg * 8;
  f32x4 acc[4][4] = {};
  for (int k0 = 0; k0 < E_; k0 += 32) {
    gl16(gA + k0,             lA);
    gl16(gA + k0 + 32 * E_,   lA + 1024);
    gl16(gA + k0 + 64 * E_,   lA + 2048);
    gl16(gA + k0 + 96 * E_,   lA + 3072);
    gl16(gB + k0,             lB);
    gl16(gB + k0 + 32 * E_,   lB + 1024);
    __syncthreads();
    short8 af[4], bf[4];
    #pragma unroll
    for (int m = 0; m < 4; ++m) af[m] = *(const short8*)(sA + (w * 64 + m * 16 + r) * 32 + kq);
    #pragma unroll
    for (int n = 0; n < 4; ++n) bf[n] = *(const short8*)(sB + (n * 16 + r) * 32 + kq);
    #pragma unroll
    for (int m = 0; m < 4; ++m)
      #pragma unroll
      for (int n = 0; n < 4; ++n)
        acc[m][n] = __builtin_amdgcn_mfma_f32_16x16x32_bf16(af[m], bf[n], acc[m][n], 0, 0, 0);
    __syncthreads();
  }
  float bs[4];
  #pragma unroll
  for (int n = 0; n < 4; ++n) bs[n] = bias[col0 + n * 16 + r];
  #pragma unroll
  for (int m = 0; m < 4; ++m) {
    #pragma unroll
    for (int j = 0; j < 4; ++j) {
      const int row_g = row0 + w * 64 + m * 16 + kg * 4 + j;
      #pragma unroll
      for (int n = 0; n < 4; ++n)
        st(out + (size_t)row_g * E_ + col0 + n * 16 + r, acc[m][n][j] + bs[n]);
    }
  }
}

// fused QKV: blockIdx.z selects weight/bias/dst (all bf16 out now)
__global__ __launch_bounds__(128) void gemm_qkv_kernel(
    const ushort* __restrict__ A,
    const ushort* __restrict__ wq, const ushort* __restrict__ wk, const ushort* __restrict__ wv,
    const float* __restrict__ bq, const float* __restrict__ bk, const float* __restrict__ bv,
    ushort* __restrict__ qb, ushort* __restrict__ kb, ushort* __restrict__ vb)
{
  const ushort* W; const float* bias; ushort* dst;
  if (blockIdx.z == 0)      { W = wq; bias = bq; dst = qb; }
  else if (blockIdx.z == 1) { W = wk; bias = bk; dst = kb; }
  else                      { W = wv; bias = bv; dst = vb; }
  gemm_tile<ushort>(A, W, bias, dst, blockIdx.x * 128, blockIdx.y * 64);
}

__global__ __launch_bounds__(128) void gemm_out_kernel(
    const ushort* __restrict__ A, const ushort* __restrict__ W,
    const float* __restrict__ bias, float* __restrict__ out)
{
  gemm_tile<float>(A, W, bias, out, blockIdx.x * 128, blockIdx.y * 64);
}

// ---------------- phi (bf16 q/k inputs) ----------------
__global__ __launch_bounds__(256) void phi_kernel(
    const ushort* __restrict__ qb, const ushort* __restrict__ kb,
    const float* __restrict__ rm, ushort* __restrict__ pq, ushort* __restrict__ pk)
{
  __shared__ float s_rm[P_ * 66];
  __shared__ float xs[4][D_];
  const int tid = threadIdx.x, w = tid >> 6, lane = tid & 63;
  const int h = blockIdx.y;
  const ushort* src = blockIdx.z ? kb : qb;
  ushort* dst = blockIdx.z ? pk : pq;
  const float* rmh = rm + (size_t)h * P_ * D_;
  for (int i = tid; i < P_ * D_; i += 256)
    s_rm[(i >> 6) * 66 + (i & 63)] = rmh[i];
  const int n = blockIdx.x * 4 + w;
  const float val = b2f(src[(size_t)n * E_ + h * D_ + lane]);
  float s2 = val * val;
  #pragma unroll
  for (int off = 32; off; off >>= 1) s2 += __shfl_xor(s2, off, 64);
  xs[w][lane] = val * (1.0f / fmaxf(sqrtf(s2), EPSV));
  __syncthreads();
  const float* rrow = s_rm + lane * 66;   // lane = p
  float acc = 0.f;
  #pragma unroll
  for (int d0 = 0; d0 < D_; d0 += 2) {
    const float2 rv = *(const float2*)(rrow + d0);
    const float2 xv = *(const float2*)(&xs[w][d0]);
    acc += rv.x * xv.x + rv.y * xv.y;
  }
  const size_t base = ((size_t)n * H_ + h) * K2 + lane;
  dst[base]      = f2b(__sinf(acc) * 0.125f);   // P^-0.5
  dst[base + 64] = f2b(__cosf(acc) * 0.125f);
}

// ---------------- chunk_sum via MFMA: cS[k2][d] = sum_tau pk[tau][k2]*v[tau][d] ----------------
__global__ __launch_bounds__(256) void chunk_sum_kernel(
    const ushort* __restrict__ pk, const ushort* __restrict__ v,
    float* __restrict__ cS, float* __restrict__ cz)
{
  const int c = blockIdx.x, bh = blockIdx.y, b = bh >> 3, h = bh & 7;
  __shared__ ushort pkT[K2][88];   // [k2][tau], row 176B: 16B-aligned, 2-way banks
  __shared__ ushort vT[D_][88];    // [d][tau]
  const int tid = threadIdx.x;
  for (int i = tid; i < CHK * 16; i += 256) {
    const int tt = i >> 4, k8 = (i & 15) * 8;
    const int n = (c * CHK + tt) * B_ + b;
    const ushort4 u0 = *(const ushort4*)(pk + ((size_t)n * H_ + h) * K2 + k8);
    const ushort4 u1 = *(const ushort4*)(pk + ((size_t)n * H_ + h) * K2 + k8 + 4);
    pkT[k8+0][tt] = u0.x; pkT[k8+1][tt] = u0.y; pkT[k8+2][tt] = u0.z; pkT[k8+3][tt] = u0.w;
    pkT[k8+4][tt] = u1.x; pkT[k8+5][tt] = u1.y; pkT[k8+6][tt] = u1.z; pkT[k8+7][tt] = u1.w;
  }
  for (int i = tid; i < CHK * 16; i += 256) {
    const int tt = i >> 4, d4 = (i & 15) * 4;
    const int n = (c * CHK + tt) * B_ + b;
    const ushort4 u = *(const ushort4*)(v + (size_t)n * E_ + h * D_ + d4);
    vT[d4+0][tt] = u.x; vT[d4+1][tt] = u.y; vT[d4+2][tt] = u.z; vT[d4+3][tt] = u.w;
  }
  __syncthreads();
  const int w = tid >> 6, lane = tid & 63;
  const int r = lane & 15, kb = lane >> 4;
  const int m0 = w * 32;
  f32x4 acc[2][4] = {};
  #pragma unroll
  for (int k0 = 0; k0 < CHK; k0 += 32) {
    const short8 a0 = *(const short8*)(&pkT[m0 + r][k0 + kb * 8]);
    const short8 a1 = *(const short8*)(&pkT[m0 + 16 + r][k0 + kb * 8]);
    #pragma unroll
    for (int nt = 0; nt < 4; ++nt) {
      const short8 bv = *(const short8*)(&vT[nt * 16 + r][k0 + kb * 8]);
      acc[0][nt] = __builtin_amdgcn_mfma_f32_16x16x32_bf16(a0, bv, acc[0][nt], 0, 0, 0);
      acc[1][nt] = __builtin_amdgcn_mfma_f32_16x16x32_bf16(a1, bv, acc[1][nt], 0, 0, 0);
    }
  }
  float* So = cS + (size_t)(c * BH + bh) * (K2 * D_);
  #pragma unroll
  for (int mt = 0; mt < 2; ++mt)
    #pragma unroll
    for (int nt = 0; nt < 4; ++nt)
      #pragma unroll
      for (int j = 0; j < 4; ++j)
        So[(m0 + mt * 16 + kb * 4 + j) * D_ + nt * 16 + r] = acc[mt][nt][j];
  if (tid < K2) {
    float zacc = 0.f;
    #pragma unroll
    for (int i2 = 0; i2 < CHK / 2; ++i2) {
      const uint u = *(const uint*)(&pkT[tid][i2 * 2]);
      zacc += lo16(u) + hi16(u);
    }
    cz[(size_t)(c * BH + bh) * K2 + tid] = zacc;
  }
}

// ---------------- exclusive prefix over chunks (coalesced, 1 elem/thread) ----------------
__global__ __launch_bounds__(256) void prefix_kernel(
    float* __restrict__ cS, float* __restrict__ cz)
{
  const int gid = blockIdx.x * 256 + threadIdx.x;   // 262144 threads
  const int bh = gid >> 13, rem = gid & 8191;
  float run = 0.f;
  #pragma unroll
  for (int c = 0; c < NC; ++c) {
    float* p = cS + (((size_t)(c * BH + bh)) << 13) + rem;
    const float t = *p; *p = run; run += t;
  }
  if (gid < BH * K2) {
    const int zbh = gid >> 7, k2 = gid & 127;
    float rz = 0.f;
    #pragma unroll
    for (int c = 0; c < NC; ++c) {
      float* pz = cz + (size_t)(c * BH + zbh) * K2 + k2;
      const float t = *pz; *pz = rz; rz += t;
    }
  }
}

// ---------------- chunk_out via MFMA ----------------
// A = causal(pq@pk^T); attn = (A@v + pq@Sp) / max(rowsum(A)+pq@zp, eps)
__global__ __launch_bounds__(256) void chunk_out_kernel(
    const ushort* __restrict__ pq, const ushort* __restrict__ pkg,
    const ushort* __restrict__ v, const float* __restrict__ Sp,
    const float* __restrict__ zp, ushort* __restrict__ attn)
{
  const int c = blockIdx.x, bh = blockIdx.y, b = bh >> 3, h = bh & 7;
  __shared__ ushort pq_s[CHK][136];   // 272B rows: 16B-aligned, 2-way banks
  __shared__ ushort pk_s[CHK][136];
  __shared__ ushort SpT_s[D_][136];   // [d][k2] bf16
  __shared__ ushort vT_s[D_][88];     // [d][tau]
  __shared__ ushort Am_s[CHK][88];    // masked A bf16 [t][tau]
  __shared__ float zps[K2];
  __shared__ float dens_s[CHK];
  __shared__ float inv_s[CHK];
  const int tid = threadIdx.x;
  for (int i = tid; i < CHK * 16; i += 256) {
    const int tt = i >> 4, k8 = (i & 15) * 8;
    const int n = (c * CHK + tt) * B_ + b;
    const size_t off = ((size_t)n * H_ + h) * K2 + k8;
    *(uint4*)(&pq_s[tt][k8]) = *(const uint4*)(pq + off);
    *(uint4*)(&pk_s[tt][k8]) = *(const uint4*)(pkg + off);
  }
  for (int i = tid; i < CHK * 16; i += 256) {
    const int tt = i >> 4, d4 = (i & 15) * 4;
    const int n = (c * CHK + tt) * B_ + b;
    const ushort4 u = *(const ushort4*)(v + (size_t)n * E_ + h * D_ + d4);
    vT_s[d4+0][tt] = u.x; vT_s[d4+1][tt] = u.y; vT_s[d4+2][tt] = u.z; vT_s[d4+3][tt] = u.w;
  }
  const float* Spb = Sp + (size_t)(c * BH + bh) * (K2 * D_);
  for (int i = tid; i < K2 * 16; i += 256) {
    const int k2 = i >> 4, d4 = (i & 15) * 4;
    const float4 s = *(const float4*)(Spb + k2 * D_ + d4);
    SpT_s[d4+0][k2] = f2b(s.x); SpT_s[d4+1][k2] = f2b(s.y);
    SpT_s[d4+2][k2] = f2b(s.z); SpT_s[d4+3][k2] = f2b(s.w);
  }
  if (tid < K2) zps[tid] = zp[(size_t)(c * BH + bh) * K2 + tid];
  __syncthreads();

  const int w = tid >> 6, lane = tid & 63;
  const int r = lane & 15, kb = lane >> 4;
  const int m0 = w * 16;                 // wave's 16 output rows
  // ---- QK^T ----
  f32x4 accA[4] = {};
  #pragma unroll
  for (int k0 = 0; k0 < K2; k0 += 32) {
    const short8 aq = *(const short8*)(&pq_s[m0 + r][k0 + kb * 8]);
    #pragma unroll
    for (int nt = 0; nt < 4; ++nt) {
      const short8 bk = *(const short8*)(&pk_s[nt * 16 + r][k0 + kb * 8]);
      accA[nt] = __builtin_amdgcn_mfma_f32_16x16x32_bf16(aq, bk, accA[nt], 0, 0, 0);
    }
  }
  // ---- mask + rowsum + Am -> LDS (bf16) ----
  float rs[4] = {0.f, 0.f, 0.f, 0.f};
  #pragma unroll
  for (int nt = 0; nt < 4; ++nt) {
    #pragma unroll
    for (int j = 0; j < 4; ++j) {
      const int row = kb * 4 + j, col = nt * 16 + r;   // chunk-local
      float a = accA[nt][j];
      a = (col <= m0 + row) ? a : 0.f;
      rs[j] += a;
      Am_s[m0 + row][col] = f2b(a);
    }
  }
  #pragma unroll
  for (int off = 1; off < 16; off <<= 1) {
    rs[0] += __shfl_xor(rs[0], off, 64);
    rs[1] += __shfl_xor(rs[1], off, 64);
    rs[2] += __shfl_xor(rs[2], off, 64);
    rs[3] += __shfl_xor(rs[3], off, 64);
  }
  if (r == 0) {
    #pragma unroll
    for (int j = 0; j < 4; ++j) dens_s[m0 + kb * 4 + j] = rs[j];
  }
  // ---- numerator: Am@v + pq@Sp (same accumulators) ----
  f32x4 accO[4] = {};
  #pragma unroll
  for (int k0 = 0; k0 < CHK; k0 += 32) {
    const short8 aa = *(const short8*)(&Am_s[m0 + r][k0 + kb * 8]);
    #pragma unroll
    for (int nt = 0; nt < 4; ++nt) {
      const short8 bv = *(const short8*)(&vT_s[nt * 16 + r][k0 + kb * 8]);
      accO[nt] = __builtin_amdgcn_mfma_f32_16x16x32_bf16(aa, bv, accO[nt], 0, 0, 0);
    }
  }
  #pragma unroll
  for (int k0 = 0; k0 < K2; k0 += 32) {
    const short8 aq = *(const short8*)(&pq_s[m0 + r][k0 + kb * 8]);
    #pragma unroll
    for (int nt = 0; nt < 4; ++nt) {
      const short8 bs = *(const short8*)(&SpT_s[nt * 16 + r][k0 + kb * 8]);
      accO[nt] = __builtin_amdgcn_mfma_f32_16x16x32_bf16(aq, bs, accO[nt], 0, 0, 0);
    }
  }
  // ---- denominator: dens + pq.zp ----
  {
    const int t_loc = m0 + (lane >> 2), seg = lane & 3;
    float qz = 0.f;
    #pragma unroll
    for (int ii = 0; ii < 16; ++ii) {
      const uint u = *(const uint*)(&pq_s[t_loc][seg * 32 + ii * 2]);
      qz += lo16(u) * zps[seg * 32 + ii * 2] + hi16(u) * zps[seg * 32 + ii * 2 + 1];
    }
    qz += __shfl_xor(qz, 1, 64);
    qz += __shfl_xor(qz, 2, 64);
    if (seg == 0) inv_s[t_loc] = 1.0f / fmaxf(dens_s[t_loc] + qz, EPSV);
  }
  // ---- epilogue ----
  #pragma unroll
  for (int j = 0; j < 4; ++j) {
    const int row = m0 + kb * 4 + j;
    const float inv = inv_s[row];
    const int n = (c * CHK + row) * B_ + b;
    ushort* op = attn + (size_t)n * E_ + h * D_;
    #pragma unroll
    for (int nt = 0; nt < 4; ++nt) op[nt * 16 + r] = f2b(accO[nt][j] * inv);
  }
}

extern "C" void kernel_launch(void* const* d_in, const int* in_sizes, int n_in,
                              void* d_out, int out_size, void* d_ws, size_t ws_size,
                              hipStream_t stream) {
  const float* x  = (const float*)d_in[0];
  const float* rm = (const float*)d_in[1];
  const float* Wq = (const float*)d_in[2];
  const float* bq = (const float*)d_in[3];
  const float* Wk = (const float*)d_in[4];
  const float* bk = (const float*)d_in[5];
  const float* Wv = (const float*)d_in[6];
  const float* bv = (const float*)d_in[7];
  const float* Wo = (const float*)d_in[8];
  const float* bo = (const float*)d_in[9];
  float* out = (float*)d_out;

  // ws layout (~54 MB, ws is 256 MiB)
  ushort* xb  = (ushort*)d_ws;                    // [N,E] bf16
  ushort* wqb = xb + (size_t)N_ * E_;             // [E,E] bf16
  ushort* wkb = wqb + (size_t)E_ * E_;
  ushort* wvb = wkb + (size_t)E_ * E_;
  ushort* wob = wvb + (size_t)E_ * E_;
  ushort* qb  = wob + (size_t)E_ * E_;            // [N,E] bf16
  ushort* kb  = qb + (size_t)N_ * E_;             // [N,E] bf16
  ushort* vb  = kb + (size_t)N_ * E_;             // [N,E] bf16
  ushort* pqb = vb + (size_t)N_ * E_;             // [N,H,K2] bf16
  ushort* pkb = pqb + (size_t)N_ * H_ * K2;       // [N,H,K2] bf16
  ushort* attnb = pkb + (size_t)N_ * H_ * K2;     // [N,E] bf16
  float* cS = (float*)(attnb + (size_t)N_ * E_);  // [NC,BH,K2,D] f32
  float* cz = cS + (size_t)NC * BH * K2 * D_;     // [NC,BH,K2] f32

  cast_kernel<<<dim3(512, 5), dim3(256), 0, stream>>>(x, Wq, Wk, Wv, Wo, xb, wqb, wkb, wvb, wob);
  gemm_qkv_kernel<<<dim3(N_ / 128, E_ / 64, 3), dim3(128), 0, stream>>>(
      xb, wqb, wkb, wvb, bq, bk, bv, qb, kb, vb);
  phi_kernel<<<dim3(N_ / 4, H_, 2), dim3(256), 0, stream>>>(qb, kb, rm, pqb, pkb);
  chunk_sum_kernel<<<dim3(NC, BH), dim3(256), 0, stream>>>(pkb, vb, cS, cz);
  prefix_kernel<<<dim3(1024), dim3(256), 0, stream>>>(cS, cz);
  chunk_out_kernel<<<dim3(NC, BH), dim3(256), 0, stream>>>(pqb, pkb, vb, cS, cz, attnb);
  gemm_out_kernel<<<dim3(N_ / 128, E_ / 64), dim3(128), 0, stream>>>(attnb, wob, bo, out);
}

// Round 6
// 68.294 us; speedup vs baseline: 5.7469x; 1.4922x over previous
//
#include <hip/hip_runtime.h>

#define T_ 1024
#define B_ 4
#define E_ 512
#define H_ 8
#define D_ 64
#define P_ 64
#define K2 128            // 2P
#define N_ (T_*B_)        // 4096 rows (t*B + b)
#define CHK 64            // scan chunk length
#define NC (T_/CHK)       // 16 chunks
#define BH (B_*H_)        // 32
#define EPSV 1e-6f

typedef unsigned int uint;
typedef unsigned short ushort;
typedef short short8 __attribute__((ext_vector_type(8)));   // 8 bf16 (MFMA A/B frag)
typedef float f32x4 __attribute__((ext_vector_type(4)));    // MFMA C/D frag

__device__ __forceinline__ float b2f(ushort u){ return __uint_as_float(((uint)u) << 16); }
__device__ __forceinline__ ushort f2b(float f){
  uint x = __float_as_uint(f);
  return (ushort)((x + 0x7fffu + ((x >> 16) & 1u)) >> 16);   // RNE
}
__device__ __forceinline__ float lo16(uint u){ return __uint_as_float(u << 16); }
__device__ __forceinline__ float hi16(uint u){ return __uint_as_float(u & 0xffff0000u); }
__device__ __forceinline__ void st(float* p, float v){ *p = v; }
__device__ __forceinline__ void st(ushort* p, float v){ *p = f2b(v); }

// async global->LDS, 16B per lane; LDS dest = wave-uniform base + lane*16 (m104)
__device__ __forceinline__ void gl16(const ushort* g, ushort* lds) {
  __builtin_amdgcn_global_load_lds(
      (const __attribute__((address_space(1))) uint*)g,
      (__attribute__((address_space(3))) uint*)lds, 16, 0, 0);
}

// ---------------- cast f32 -> bf16 (x + 4 weights + rm) ----------------
__global__ __launch_bounds__(256) void cast_kernel(
    const float* __restrict__ x, const float* __restrict__ wq, const float* __restrict__ wk,
    const float* __restrict__ wv, const float* __restrict__ wo, const float* __restrict__ rm,
    ushort* __restrict__ xb, ushort* __restrict__ wqb, ushort* __restrict__ wkb,
    ushort* __restrict__ wvb, ushort* __restrict__ wob, ushort* __restrict__ rmb)
{
  const float* src; ushort* dst; int n4;
  switch (blockIdx.y) {
    case 0:  src = x;  dst = xb;  n4 = N_ * E_ / 4; break;
    case 1:  src = wq; dst = wqb; n4 = E_ * E_ / 4; break;
    case 2:  src = wk; dst = wkb; n4 = E_ * E_ / 4; break;
    case 3:  src = wv; dst = wvb; n4 = E_ * E_ / 4; break;
    case 4:  src = wo; dst = wob; n4 = E_ * E_ / 4; break;
    default: src = rm; dst = rmb; n4 = H_ * P_ * D_ / 4; break;
  }
  const int stride = gridDim.x * 256;
  for (int i = blockIdx.x * 256 + threadIdx.x; i < n4; i += stride) {
    const float4 v = *(const float4*)(src + (size_t)i * 4);
    ushort4 o; o.x = f2b(v.x); o.y = f2b(v.y); o.z = f2b(v.z); o.w = f2b(v.w);
    *(ushort4*)(dst + (size_t)i * 4) = o;
  }
}

// ---------------- LDS-staged MFMA GEMM tile: 128x64, BK=32, 2 waves ----------------
template<typename OutT>
__device__ __forceinline__ void gemm_tile(
    const ushort* __restrict__ A, const ushort* __restrict__ W,
    const float* __restrict__ bias, OutT* __restrict__ out,
    const int row0, const int col0)
{
  __shared__ ushort sA[128 * 32];   // [row][k] rows of 64B, linear
  __shared__ ushort sB[64 * 32];
  const int tid = threadIdx.x, w = tid >> 6, lane = tid & 63;
  const int lrow = lane >> 2, lk8 = (lane & 3) * 8;
  const ushort* gA = A + (size_t)(row0 + w * 16 + lrow) * E_ + lk8;
  const ushort* gB = W + (size_t)(col0 + w * 16 + lrow) * E_ + lk8;
  ushort* lA = sA + w * 512;
  ushort* lB = sB + w * 512;
  const int r = lane & 15, kg = lane >> 4, kq = kg * 8;
  f32x4 acc[4][4] = {};
  for (int k0 = 0; k0 < E_; k0 += 32) {
    gl16(gA + k0,             lA);
    gl16(gA + k0 + 32 * E_,   lA + 1024);
    gl16(gA + k0 + 64 * E_,   lA + 2048);
    gl16(gA + k0 + 96 * E_,   lA + 3072);
    gl16(gB + k0,             lB);
    gl16(gB + k0 + 32 * E_,   lB + 1024);
    __syncthreads();
    short8 af[4], bf[4];
    #pragma unroll
    for (int m = 0; m < 4; ++m) af[m] = *(const short8*)(sA + (w * 64 + m * 16 + r) * 32 + kq);
    #pragma unroll
    for (int n = 0; n < 4; ++n) bf[n] = *(const short8*)(sB + (n * 16 + r) * 32 + kq);
    #pragma unroll
    for (int m = 0; m < 4; ++m)
      #pragma unroll
      for (int n = 0; n < 4; ++n)
        acc[m][n] = __builtin_amdgcn_mfma_f32_16x16x32_bf16(af[m], bf[n], acc[m][n], 0, 0, 0);
    __syncthreads();
  }
  float bs[4];
  #pragma unroll
  for (int n = 0; n < 4; ++n) bs[n] = bias[col0 + n * 16 + r];
  #pragma unroll
  for (int m = 0; m < 4; ++m) {
    #pragma unroll
    for (int j = 0; j < 4; ++j) {
      const int row_g = row0 + w * 64 + m * 16 + kg * 4 + j;
      #pragma unroll
      for (int n = 0; n < 4; ++n)
        st(out + (size_t)row_g * E_ + col0 + n * 16 + r, acc[m][n][j] + bs[n]);
    }
  }
}

__global__ __launch_bounds__(128) void gemm_qkv_kernel(
    const ushort* __restrict__ A,
    const ushort* __restrict__ wq, const ushort* __restrict__ wk, const ushort* __restrict__ wv,
    const float* __restrict__ bq, const float* __restrict__ bk, const float* __restrict__ bv,
    ushort* __restrict__ qb, ushort* __restrict__ kb, ushort* __restrict__ vb)
{
  const ushort* W; const float* bias; ushort* dst;
  if (blockIdx.z == 0)      { W = wq; bias = bq; dst = qb; }
  else if (blockIdx.z == 1) { W = wk; bias = bk; dst = kb; }
  else                      { W = wv; bias = bv; dst = vb; }
  gemm_tile<ushort>(A, W, bias, dst, blockIdx.x * 128, blockIdx.y * 64);
}

__global__ __launch_bounds__(128) void gemm_out_kernel(
    const ushort* __restrict__ A, const ushort* __restrict__ W,
    const float* __restrict__ bias, float* __restrict__ out)
{
  gemm_tile<float>(A, W, bias, out, blockIdx.x * 128, blockIdx.y * 64);
}

// ---------------- phi via MFMA ----------------
// proj[n,p] = (q[n,:] . rm[h,p,:]) / max(||q[n,:]||, eps); out = [sin,cos](proj)*0.125
// Block: 64-row n-tile x one h x (q|k). 4 waves, each 16 rows x 64 p = 8 MFMA.
__global__ __launch_bounds__(256) void phi_kernel(
    const ushort* __restrict__ qb, const ushort* __restrict__ kb,
    const ushort* __restrict__ rmb, ushort* __restrict__ pq, ushort* __restrict__ pk)
{
  __shared__ ushort xq[64][72];    // q tile [n][d], stride 144B -> 2-way banks on frag reads
  __shared__ ushort rms[64][72];   // rm[h]  [p][d]
  __shared__ float inv_s[64];
  const int tid = threadIdx.x;
  const int h = blockIdx.y;
  const ushort* src = blockIdx.z ? kb : qb;
  ushort* dst = blockIdx.z ? pk : pq;
  const int n0 = blockIdx.x * 64;
  const int row = tid >> 2, seg = (tid & 3) * 16;
  {
    const ushort* gq = src + (size_t)(n0 + row) * E_ + h * D_ + seg;
    const ushort* gr = rmb + ((size_t)h * P_ + row) * D_ + seg;
    const uint4 q0 = *(const uint4*)(gq);
    const uint4 q1 = *(const uint4*)(gq + 8);
    *(uint4*)(&xq[row][seg])      = q0;
    *(uint4*)(&xq[row][seg + 8])  = q1;
    *(uint4*)(&rms[row][seg])     = *(const uint4*)(gr);
    *(uint4*)(&rms[row][seg + 8]) = *(const uint4*)(gr + 8);
    // row sum-of-squares from the just-loaded registers
    float s2 = 0.f;
    const uint* qw = (const uint*)&q0;
    #pragma unroll
    for (int i = 0; i < 4; ++i) { const float a = lo16(qw[i]), b = hi16(qw[i]); s2 += a*a + b*b; }
    const uint* qw1 = (const uint*)&q1;
    #pragma unroll
    for (int i = 0; i < 4; ++i) { const float a = lo16(qw1[i]), b = hi16(qw1[i]); s2 += a*a + b*b; }
    s2 += __shfl_xor(s2, 1, 64);
    s2 += __shfl_xor(s2, 2, 64);
    if ((tid & 3) == 0) inv_s[row] = 1.0f / fmaxf(sqrtf(s2), EPSV);
  }
  __syncthreads();
  const int w = tid >> 6, lane = tid & 63;
  const int r = lane & 15, kg = lane >> 4;
  const int m0 = w * 16;
  f32x4 acc[4] = {};
  #pragma unroll
  for (int k0 = 0; k0 < D_; k0 += 32) {
    const short8 a = *(const short8*)(&xq[m0 + r][k0 + kg * 8]);
    #pragma unroll
    for (int nt = 0; nt < 4; ++nt) {
      const short8 bfr = *(const short8*)(&rms[nt * 16 + r][k0 + kg * 8]);
      acc[nt] = __builtin_amdgcn_mfma_f32_16x16x32_bf16(a, bfr, acc[nt], 0, 0, 0);
    }
  }
  #pragma unroll
  for (int j = 0; j < 4; ++j) {
    const int rr = m0 + kg * 4 + j;
    const float inv = inv_s[rr];
    const size_t base = ((size_t)(n0 + rr) * H_ + h) * K2;
    #pragma unroll
    for (int nt = 0; nt < 4; ++nt) {
      const int p = nt * 16 + r;
      const float proj = acc[nt][j] * inv;
      dst[base + p]      = f2b(__sinf(proj) * 0.125f);   // P^-0.5
      dst[base + 64 + p] = f2b(__cosf(proj) * 0.125f);
    }
  }
}

// ---------------- chunk_sum via MFMA: cS[k2][d] = sum_tau pk[tau][k2]*v[tau][d] ----------------
__global__ __launch_bounds__(256) void chunk_sum_kernel(
    const ushort* __restrict__ pk, const ushort* __restrict__ v,
    float* __restrict__ cS, float* __restrict__ cz)
{
  const int c = blockIdx.x, bh = blockIdx.y, b = bh >> 3, h = bh & 7;
  __shared__ ushort pkT[K2][88];   // [k2][tau]
  __shared__ ushort vT[D_][88];    // [d][tau]
  const int tid = threadIdx.x;
  for (int i = tid; i < CHK * 16; i += 256) {
    const int tt = i >> 4, k8 = (i & 15) * 8;
    const int n = (c * CHK + tt) * B_ + b;
    const ushort4 u0 = *(const ushort4*)(pk + ((size_t)n * H_ + h) * K2 + k8);
    const ushort4 u1 = *(const ushort4*)(pk + ((size_t)n * H_ + h) * K2 + k8 + 4);
    pkT[k8+0][tt] = u0.x; pkT[k8+1][tt] = u0.y; pkT[k8+2][tt] = u0.z; pkT[k8+3][tt] = u0.w;
    pkT[k8+4][tt] = u1.x; pkT[k8+5][tt] = u1.y; pkT[k8+6][tt] = u1.z; pkT[k8+7][tt] = u1.w;
  }
  for (int i = tid; i < CHK * 16; i += 256) {
    const int tt = i >> 4, d4 = (i & 15) * 4;
    const int n = (c * CHK + tt) * B_ + b;
    const ushort4 u = *(const ushort4*)(v + (size_t)n * E_ + h * D_ + d4);
    vT[d4+0][tt] = u.x; vT[d4+1][tt] = u.y; vT[d4+2][tt] = u.z; vT[d4+3][tt] = u.w;
  }
  __syncthreads();
  const int w = tid >> 6, lane = tid & 63;
  const int r = lane & 15, kb = lane >> 4;
  const int m0 = w * 32;
  f32x4 acc[2][4] = {};
  #pragma unroll
  for (int k0 = 0; k0 < CHK; k0 += 32) {
    const short8 a0 = *(const short8*)(&pkT[m0 + r][k0 + kb * 8]);
    const short8 a1 = *(const short8*)(&pkT[m0 + 16 + r][k0 + kb * 8]);
    #pragma unroll
    for (int nt = 0; nt < 4; ++nt) {
      const short8 bv = *(const short8*)(&vT[nt * 16 + r][k0 + kb * 8]);
      acc[0][nt] = __builtin_amdgcn_mfma_f32_16x16x32_bf16(a0, bv, acc[0][nt], 0, 0, 0);
      acc[1][nt] = __builtin_amdgcn_mfma_f32_16x16x32_bf16(a1, bv, acc[1][nt], 0, 0, 0);
    }
  }
  float* So = cS + (size_t)(c * BH + bh) * (K2 * D_);
  #pragma unroll
  for (int mt = 0; mt < 2; ++mt)
    #pragma unroll
    for (int nt = 0; nt < 4; ++nt)
      #pragma unroll
      for (int j = 0; j < 4; ++j)
        So[(m0 + mt * 16 + kb * 4 + j) * D_ + nt * 16 + r] = acc[mt][nt][j];
  if (tid < K2) {
    float zacc = 0.f;
    #pragma unroll
    for (int i2 = 0; i2 < CHK / 2; ++i2) {
      const uint u = *(const uint*)(&pkT[tid][i2 * 2]);
      zacc += lo16(u) + hi16(u);
    }
    cz[(size_t)(c * BH + bh) * K2 + tid] = zacc;
  }
}

// ---------------- exclusive prefix over chunks (coalesced, 1 elem/thread) ----------------
__global__ __launch_bounds__(256) void prefix_kernel(
    float* __restrict__ cS, float* __restrict__ cz)
{
  const int gid = blockIdx.x * 256 + threadIdx.x;
  const int bh = gid >> 13, rem = gid & 8191;
  float run = 0.f;
  #pragma unroll
  for (int c = 0; c < NC; ++c) {
    float* p = cS + (((size_t)(c * BH + bh)) << 13) + rem;
    const float t = *p; *p = run; run += t;
  }
  if (gid < BH * K2) {
    const int zbh = gid >> 7, k2 = gid & 127;
    float rz = 0.f;
    #pragma unroll
    for (int c = 0; c < NC; ++c) {
      float* pz = cz + (size_t)(c * BH + zbh) * K2 + k2;
      const float t = *pz; *pz = rz; rz += t;
    }
  }
}

// ---------------- chunk_out via MFMA ----------------
__global__ __launch_bounds__(256) void chunk_out_kernel(
    const ushort* __restrict__ pq, const ushort* __restrict__ pkg,
    const ushort* __restrict__ v, const float* __restrict__ Sp,
    const float* __restrict__ zp, ushort* __restrict__ attn)
{
  const int c = blockIdx.x, bh = blockIdx.y, b = bh >> 3, h = bh & 7;
  __shared__ ushort pq_s[CHK][136];
  __shared__ ushort pk_s[CHK][136];
  __shared__ ushort SpT_s[D_][136];
  __shared__ ushort vT_s[D_][88];
  __shared__ ushort Am_s[CHK][88];
  __shared__ float zps[K2];
  __shared__ float dens_s[CHK];
  __shared__ float inv_s[CHK];
  const int tid = threadIdx.x;
  for (int i = tid; i < CHK * 16; i += 256) {
    const int tt = i >> 4, k8 = (i & 15) * 8;
    const int n = (c * CHK + tt) * B_ + b;
    const size_t off = ((size_t)n * H_ + h) * K2 + k8;
    *(uint4*)(&pq_s[tt][k8]) = *(const uint4*)(pq + off);
    *(uint4*)(&pk_s[tt][k8]) = *(const uint4*)(pkg + off);
  }
  for (int i = tid; i < CHK * 16; i += 256) {
    const int tt = i >> 4, d4 = (i & 15) * 4;
    const int n = (c * CHK + tt) * B_ + b;
    const ushort4 u = *(const ushort4*)(v + (size_t)n * E_ + h * D_ + d4);
    vT_s[d4+0][tt] = u.x; vT_s[d4+1][tt] = u.y; vT_s[d4+2][tt] = u.z; vT_s[d4+3][tt] = u.w;
  }
  const float* Spb = Sp + (size_t)(c * BH + bh) * (K2 * D_);
  for (int i = tid; i < K2 * 16; i += 256) {
    const int k2 = i >> 4, d4 = (i & 15) * 4;
    const float4 s = *(const float4*)(Spb + k2 * D_ + d4);
    SpT_s[d4+0][k2] = f2b(s.x); SpT_s[d4+1][k2] = f2b(s.y);
    SpT_s[d4+2][k2] = f2b(s.z); SpT_s[d4+3][k2] = f2b(s.w);
  }
  if (tid < K2) zps[tid] = zp[(size_t)(c * BH + bh) * K2 + tid];
  __syncthreads();

  const int w = tid >> 6, lane = tid & 63;
  const int r = lane & 15, kb = lane >> 4;
  const int m0 = w * 16;
  f32x4 accA[4] = {};
  #pragma unroll
  for (int k0 = 0; k0 < K2; k0 += 32) {
    const short8 aq = *(const short8*)(&pq_s[m0 + r][k0 + kb * 8]);
    #pragma unroll
    for (int nt = 0; nt < 4; ++nt) {
      const short8 bk = *(const short8*)(&pk_s[nt * 16 + r][k0 + kb * 8]);
      accA[nt] = __builtin_amdgcn_mfma_f32_16x16x32_bf16(aq, bk, accA[nt], 0, 0, 0);
    }
  }
  float rs[4] = {0.f, 0.f, 0.f, 0.f};
  #pragma unroll
  for (int nt = 0; nt < 4; ++nt) {
    #pragma unroll
    for (int j = 0; j < 4; ++j) {
      const int row = kb * 4 + j, col = nt * 16 + r;
      float a = accA[nt][j];
      a = (col <= m0 + row) ? a : 0.f;
      rs[j] += a;
      Am_s[m0 + row][col] = f2b(a);
    }
  }
  #pragma unroll
  for (int off = 1; off < 16; off <<= 1) {
    rs[0] += __shfl_xor(rs[0], off, 64);
    rs[1] += __shfl_xor(rs[1], off, 64);
    rs[2] += __shfl_xor(rs[2], off, 64);
    rs[3] += __shfl_xor(rs[3], off, 64);
  }
  if (r == 0) {
    #pragma unroll
    for (int j = 0; j < 4; ++j) dens_s[m0 + kb * 4 + j] = rs[j];
  }
  f32x4 accO[4] = {};
  #pragma unroll
  for (int k0 = 0; k0 < CHK; k0 += 32) {
    const short8 aa = *(const short8*)(&Am_s[m0 + r][k0 + kb * 8]);
    #pragma unroll
    for (int nt = 0; nt < 4; ++nt) {
      const short8 bv = *(const short8*)(&vT_s[nt * 16 + r][k0 + kb * 8]);
      accO[nt] = __builtin_amdgcn_mfma_f32_16x16x32_bf16(aa, bv, accO[nt], 0, 0, 0);
    }
  }
  #pragma unroll
  for (int k0 = 0; k0 < K2; k0 += 32) {
    const short8 aq = *(const short8*)(&pq_s[m0 + r][k0 + kb * 8]);
    #pragma unroll
    for (int nt = 0; nt < 4; ++nt) {
      const short8 bs = *(const short8*)(&SpT_s[nt * 16 + r][k0 + kb * 8]);
      accO[nt] = __builtin_amdgcn_mfma_f32_16x16x32_bf16(aq, bs, accO[nt], 0, 0, 0);
    }
  }
  {
    const int t_loc = m0 + (lane >> 2), seg = lane & 3;
    float qz = 0.f;
    #pragma unroll
    for (int ii = 0; ii < 16; ++ii) {
      const uint u = *(const uint*)(&pq_s[t_loc][seg * 32 + ii * 2]);
      qz += lo16(u) * zps[seg * 32 + ii * 2] + hi16(u) * zps[seg * 32 + ii * 2 + 1];
    }
    qz += __shfl_xor(qz, 1, 64);
    qz += __shfl_xor(qz, 2, 64);
    if (seg == 0) inv_s[t_loc] = 1.0f / fmaxf(dens_s[t_loc] + qz, EPSV);
  }
  #pragma unroll
  for (int j = 0; j < 4; ++j) {
    const int row = m0 + kb * 4 + j;
    const float inv = inv_s[row];
    const int n = (c * CHK + row) * B_ + b;
    ushort* op = attn + (size_t)n * E_ + h * D_;
    #pragma unroll
    for (int nt = 0; nt < 4; ++nt) op[nt * 16 + r] = f2b(accO[nt][j] * inv);
  }
}

extern "C" void kernel_launch(void* const* d_in, const int* in_sizes, int n_in,
                              void* d_out, int out_size, void* d_ws, size_t ws_size,
                              hipStream_t stream) {
  const float* x  = (const float*)d_in[0];
  const float* rm = (const float*)d_in[1];
  const float* Wq = (const float*)d_in[2];
  const float* bq = (const float*)d_in[3];
  const float* Wk = (const float*)d_in[4];
  const float* bk = (const float*)d_in[5];
  const float* Wv = (const float*)d_in[6];
  const float* bv = (const float*)d_in[7];
  const float* Wo = (const float*)d_in[8];
  const float* bo = (const float*)d_in[9];
  float* out = (float*)d_out;

  ushort* xb  = (ushort*)d_ws;                    // [N,E] bf16
  ushort* wqb = xb + (size_t)N_ * E_;             // [E,E] bf16
  ushort* wkb = wqb + (size_t)E_ * E_;
  ushort* wvb = wkb + (size_t)E_ * E_;
  ushort* wob = wvb + (size_t)E_ * E_;
  ushort* rmb = wob + (size_t)E_ * E_;            // [H,P,D] bf16
  ushort* qb  = rmb + (size_t)H_ * P_ * D_;       // [N,E] bf16
  ushort* kb  = qb + (size_t)N_ * E_;             // [N,E] bf16
  ushort* vb  = kb + (size_t)N_ * E_;             // [N,E] bf16
  ushort* pqb = vb + (size_t)N_ * E_;             // [N,H,K2] bf16
  ushort* pkb = pqb + (size_t)N_ * H_ * K2;       // [N,H,K2] bf16
  ushort* attnb = pkb + (size_t)N_ * H_ * K2;     // [N,E] bf16
  float* cS = (float*)(attnb + (size_t)N_ * E_);  // [NC,BH,K2,D] f32
  float* cz = cS + (size_t)NC * BH * K2 * D_;     // [NC,BH,K2] f32

  cast_kernel<<<dim3(512, 6), dim3(256), 0, stream>>>(
      x, Wq, Wk, Wv, Wo, rm, xb, wqb, wkb, wvb, wob, rmb);
  gemm_qkv_kernel<<<dim3(N_ / 128, E_ / 64, 3), dim3(128), 0, stream>>>(
      xb, wqb, wkb, wvb, bq, bk, bv, qb, kb, vb);
  phi_kernel<<<dim3(N_ / 64, H_, 2), dim3(256), 0, stream>>>(qb, kb, rmb, pqb, pkb);
  chunk_sum_kernel<<<dim3(NC, BH), dim3(256), 0, stream>>>(pkb, vb, cS, cz);
  prefix_kernel<<<dim3(1024), dim3(256), 0, stream>>>(cS, cz);
  chunk_out_kernel<<<dim3(NC, BH), dim3(256), 0, stream>>>(pqb, pkb, vb, cS, cz, attnb);
  gemm_out_kernel<<<dim3(N_ / 128, E_ / 64), dim3(128), 0, stream>>>(attnb, wob, bo, out);
}